// Round 1
// baseline (943.691 us; speedup 1.0000x reference)
//
#include <hip/hip_runtime.h>
#include <math.h>

#define NN 3000
#define DD 30
#define LLEN 100
#define NDIM 256
#define PI_F 3.14159265358979323846f

// ---- output layout (float offsets) ----
#define OF_FE  0          // features_e: 9000 x 512
#define OF_ADJ 4608000    // adj_la: 9000 x 9000
#define OF_NB  85608000   // neighbor_emb: 3000 x 1536
#define OF_FT  90216000   // ft|fv|fp: 3 x (3000 x 512)

// ---- workspace layout (float offsets) ----
#define WS_BLOCKS 0       // 90 * 100 * 100
#define WS_C01 900000
#define WS_C02 903000
#define WS_C12 906000
#define WS_DINV 909000    // 9000

__device__ __forceinline__ const float* xrow(int r, const float* t, const float* v, const float* p) {
  if (r < NN) return t + (size_t)r * NDIM;
  if (r < 2*NN) return v + (size_t)(r - NN) * NDIM;
  return p + (size_t)(r - 2*NN) * NDIM;
}

// features_e[:, 0:256] = X
__global__ __launch_bounds__(256) void fillx_kernel(const float* __restrict__ t, const float* __restrict__ v,
                                                    const float* __restrict__ p, float* __restrict__ fe) {
  int r = blockIdx.x, f = threadIdx.x;
  fe[(size_t)r * 512 + f] = xrow(r, t, v, p)[f];
}

// row-normalize all 9000 feature rows
__global__ __launch_bounds__(64) void norm_kernel(const float* __restrict__ t, const float* __restrict__ v,
                                                  const float* __restrict__ p, float* __restrict__ normed) {
  int r = blockIdx.x, lane = threadIdx.x;
  const float* src = xrow(r, t, v, p);
  float4 x = ((const float4*)src)[lane];
  float ss = x.x*x.x + x.y*x.y + x.z*x.z + x.w*x.w;
  #pragma unroll
  for (int off = 32; off > 0; off >>= 1) ss += __shfl_xor(ss, off);
  float nrm = sqrtf(ss);
  float4 o = make_float4(x.x/nrm, x.y/nrm, x.z/nrm, x.w/nrm);
  ((float4*)(normed + (size_t)r * NDIM))[lane] = o;
}

// per (m,d): spital[i][j] = (1 - acos(dot_ij*0.99999)/pi) / (log(|i-j|+1)+1e-4)
// gram via LDS k-major tile, 16x16 threads x 7x7 microtile (covers 112x112 >= 100x100)
#define LPAD 112
__global__ __launch_bounds__(256) void spital_kernel(const float* __restrict__ normed, float* __restrict__ blocks) {
  int b = blockIdx.x;          // m*30+d ; node base = b*100
  int base = b * 100;
  __shared__ float Ts[64][LPAD];
  int tid = threadIdx.x;
  int tn = tid & 15, tm = tid >> 4;
  float acc[7][7];
  #pragma unroll
  for (int q = 0; q < 7; ++q)
    #pragma unroll
    for (int s = 0; s < 7; ++s) acc[q][s] = 0.0f;

  for (int kk = 0; kk < 256; kk += 64) {
    for (int pp = tid; pp < 100 * 16; pp += 256) {
      int kq = pp & 15, i = pp >> 4;
      float4 vv = *(const float4*)&normed[(size_t)(base + i) * NDIM + kk + kq * 4];
      Ts[kq*4+0][i] = vv.x; Ts[kq*4+1][i] = vv.y; Ts[kq*4+2][i] = vv.z; Ts[kq*4+3][i] = vv.w;
    }
    __syncthreads();
    #pragma unroll 4
    for (int k = 0; k < 64; ++k) {
      float a[7], bb[7];
      #pragma unroll
      for (int q = 0; q < 7; ++q) { int i = tm*7+q; if (i > 99) i = 99; a[q] = Ts[k][i]; }
      #pragma unroll
      for (int s = 0; s < 7; ++s) { int j = tn*7+s; if (j > 99) j = 99; bb[s] = Ts[k][j]; }
      #pragma unroll
      for (int q = 0; q < 7; ++q)
        #pragma unroll
        for (int s = 0; s < 7; ++s) acc[q][s] += a[q] * bb[s];
    }
    __syncthreads();
  }
  #pragma unroll
  for (int q = 0; q < 7; ++q) {
    int i = tm*7+q; if (i >= 100) continue;
    #pragma unroll
    for (int s = 0; s < 7; ++s) {
      int j = tn*7+s; if (j >= 100) continue;
      float S = acc[q][s] * 0.99999f;
      float sim = 1.0f - acosf(S) / PI_F;
      int dd = i - j; if (dd < 0) dd = -dd;
      float decay = logf((float)dd + 1.0f) + 1e-4f;
      blocks[(size_t)b * 10000 + i * 100 + j] = sim / decay;
    }
  }
}

// cross-modality diagonal sims
__global__ __launch_bounds__(64) void dsim_kernel(const float* __restrict__ normed, float* __restrict__ c01,
                                                  float* __restrict__ c02, float* __restrict__ c12) {
  int rem = blockIdx.x, lane = threadIdx.x;
  float4 a = ((const float4*)&normed[(size_t)rem * NDIM])[lane];
  float4 b = ((const float4*)&normed[(size_t)(NN + rem) * NDIM])[lane];
  float4 c = ((const float4*)&normed[(size_t)(2*NN + rem) * NDIM])[lane];
  float s01 = a.x*b.x + a.y*b.y + a.z*b.z + a.w*b.w;
  float s02 = a.x*c.x + a.y*c.y + a.z*c.z + a.w*c.w;
  float s12 = b.x*c.x + b.y*c.y + b.z*c.z + b.w*c.w;
  #pragma unroll
  for (int off = 32; off > 0; off >>= 1) {
    s01 += __shfl_xor(s01, off);
    s02 += __shfl_xor(s02, off);
    s12 += __shfl_xor(s12, off);
  }
  if (lane == 0) {
    c01[rem] = 1.0f - acosf(s01 * 0.99999f) / PI_F;
    c02[rem] = 1.0f - acosf(s02 * 0.99999f) / PI_F;
    c12[rem] = 1.0f - acosf(s12 * 0.99999f) / PI_F;
  }
}

// sequential scan: for e in 0..99 { zero 80 smallest of col e; then of row e }
// stable-argsort semantics: zero i iff #{j: v_j<v_i or (v_j==v_i && j<i)} < 80
__global__ __launch_bounds__(128) void sparsify_kernel(float* __restrict__ blocks) {
  int b = blockIdx.x;
  __shared__ float A[10000];
  __shared__ float colbuf[112];
  int tid = threadIdx.x;
  for (int p0 = tid; p0 < 10000; p0 += 128) A[p0] = blocks[(size_t)b * 10000 + p0];
  if (tid >= 100 && tid < 112) colbuf[tid] = 3.402823466e38f;
  __syncthreads();

  for (int e = 0; e < 100; ++e) {
    // ---- column phase ----
    if (tid < 100) colbuf[tid] = A[tid * 100 + e];
    __syncthreads();
    if (tid < 100) {
      float vi = colbuf[tid];
      int cnt = 0;
      #pragma unroll
      for (int q = 0; q < 28; ++q) {
        float4 vj = *(const float4*)&colbuf[q * 4];
        int j0 = q * 4;
        cnt += (vj.x < vi || (vj.x == vi && (j0+0) < tid));
        cnt += (vj.y < vi || (vj.y == vi && (j0+1) < tid));
        cnt += (vj.z < vi || (vj.z == vi && (j0+2) < tid));
        cnt += (vj.w < vi || (vj.w == vi && (j0+3) < tid));
      }
      if (cnt < 80) A[tid * 100 + e] = 0.0f;
    }
    __syncthreads();
    // ---- row phase ----
    if (tid < 100) colbuf[tid] = A[e * 100 + tid];
    __syncthreads();
    if (tid < 100) {
      float vi = colbuf[tid];
      int cnt = 0;
      #pragma unroll
      for (int q = 0; q < 28; ++q) {
        float4 vj = *(const float4*)&colbuf[q * 4];
        int j0 = q * 4;
        cnt += (vj.x < vi || (vj.x == vi && (j0+0) < tid));
        cnt += (vj.y < vi || (vj.y == vi && (j0+1) < tid));
        cnt += (vj.z < vi || (vj.z == vi && (j0+2) < tid));
        cnt += (vj.w < vi || (vj.w == vi && (j0+3) < tid));
      }
      if (cnt < 80) A[e * 100 + tid] = 0.0f;
    }
    __syncthreads();
  }
  for (int p0 = tid; p0 < 10000; p0 += 128) blocks[(size_t)b * 10000 + p0] = A[p0];
}

// degree -> dinv
__global__ __launch_bounds__(256) void deg_kernel(const float* __restrict__ blocks, const float* __restrict__ c01,
                                                  const float* __restrict__ c02, const float* __restrict__ c12,
                                                  float* __restrict__ dinv) {
  int r = blockIdx.x * 256 + threadIdx.x;
  if (r >= 3*NN) return;
  int m = r / NN, rem = r % NN;
  int d = rem / 100, i = rem % 100;
  const float* row = &blocks[((size_t)(m*DD + d)) * 10000 + i * 100];
  float s = 0.0f;
  for (int j = 0; j < 100; ++j) s += row[j];
  if (m == 0) s += c01[rem] + c02[rem];
  else if (m == 1) s += c01[rem] + c12[rem];
  else s += c02[rem] + c12[rem];
  if (s == 0.0f) s = 1e-12f;
  dinv[r] = 1.0f / sqrtf(s);
}

// blocks *= dinv_r * dinv_c (in place)
__global__ __launch_bounds__(256) void normblocks_kernel(float* __restrict__ blocks, const float* __restrict__ dinv) {
  int p = blockIdx.x * 256 + threadIdx.x;
  if (p >= 900000) return;
  int b = p / 10000, q = p % 10000;
  int i = q / 100, j = q % 100;
  int rbase = b * 100;
  blocks[p] *= dinv[rbase + i] * dinv[rbase + j];
}

// scatter normalized blocks + cross entries into dense adj (pre-zeroed)
__global__ __launch_bounds__(256) void scatter_kernel(const float* __restrict__ blocks, const float* __restrict__ c01,
                                                      const float* __restrict__ c02, const float* __restrict__ c12,
                                                      const float* __restrict__ dinv, float* __restrict__ adj) {
  int b = blockIdx.x, m = b / DD, d = b % DD;
  int rbase = b * 100;
  for (int p = threadIdx.x; p < 10000; p += 256) {
    int i = p / 100, j = p % 100;
    adj[(size_t)(rbase + i) * 9000 + rbase + j] = blocks[(size_t)b * 10000 + p];
  }
  int tid = threadIdx.x;
  if (tid < 100) {
    int rem = d * 100 + tid;
    int r = rbase + tid;
    float dr = dinv[r];
    const float *a1, *a2; int n1, n2;
    if (m == 0)      { a1 = c01; a2 = c02; n1 = 1; n2 = 2; }
    else if (m == 1) { a1 = c01; a2 = c12; n1 = 0; n2 = 2; }
    else             { a1 = c02; a2 = c12; n1 = 0; n2 = 1; }
    adj[(size_t)r * 9000 + n1 * NN + rem] = a1[rem] * dr * dinv[n1 * NN + rem];
    adj[(size_t)r * 9000 + n2 * NN + rem] = a2[rem] * dr * dinv[n2 * NN + rem];
  }
}

// C = relu(A@W + bias)            (mode 0)
// C = relu(theta*(A@W) + omtheta*A) (mode 1, N==K==256)
__global__ __launch_bounds__(256) void gemm_kernel(const float* __restrict__ A, int lda,
                                                   const float* __restrict__ W, const float* __restrict__ bias,
                                                   float* __restrict__ C, int M, int mode,
                                                   float theta, float omtheta) {
  __shared__ float As[16][64];
  __shared__ float Bs[16][64];
  int bx = blockIdx.x & 3;
  int by = blockIdx.x >> 2;
  int tid = threadIdx.x;
  int tn = tid & 15, tm = tid >> 4;
  int row0 = by * 64, col0 = bx * 64;
  float acc[4][4];
  #pragma unroll
  for (int i = 0; i < 4; ++i)
    #pragma unroll
    for (int j = 0; j < 4; ++j) acc[i][j] = 0.0f;
  int lr = tid >> 2, lc = tid & 3;
  int br = tid >> 4, bc = tid & 15;

  for (int kk = 0; kk < 256; kk += 16) {
    int ar = row0 + lr;
    float4 av = make_float4(0.f, 0.f, 0.f, 0.f);
    if (ar < M) av = *(const float4*)&A[(size_t)ar * lda + kk + lc * 4];
    As[lc*4+0][lr] = av.x; As[lc*4+1][lr] = av.y; As[lc*4+2][lr] = av.z; As[lc*4+3][lr] = av.w;
    *(float4*)&Bs[br][bc * 4] = *(const float4*)&W[(size_t)(kk + br) * 256 + col0 + bc * 4];
    __syncthreads();
    #pragma unroll
    for (int k = 0; k < 16; ++k) {
      float4 a4 = *(const float4*)&As[k][tm * 4];
      float4 b4 = *(const float4*)&Bs[k][tn * 4];
      float a[4] = {a4.x, a4.y, a4.z, a4.w};
      float bb[4] = {b4.x, b4.y, b4.z, b4.w};
      #pragma unroll
      for (int ii = 0; ii < 4; ++ii)
        #pragma unroll
        for (int jj = 0; jj < 4; ++jj) acc[ii][jj] += a[ii] * bb[jj];
    }
    __syncthreads();
  }
  #pragma unroll
  for (int ii = 0; ii < 4; ++ii) {
    int r = row0 + tm * 4 + ii;
    if (r >= M) continue;
    #pragma unroll
    for (int jj = 0; jj < 4; ++jj) {
      int c = col0 + tn * 4 + jj;
      float val = acc[ii][jj];
      if (mode == 0) val += bias[c];
      else val = theta * val + omtheta * A[(size_t)r * lda + c];
      C[(size_t)r * 256 + c] = fmaxf(val, 0.0f);
    }
  }
}

// support = 0.9 * (adj_norm @ h) + 0.1 * h0   (block-sparse adj)
__global__ __launch_bounds__(256) void spmm_kernel(const float* __restrict__ blocks, const float* __restrict__ c01,
                                                   const float* __restrict__ c02, const float* __restrict__ c12,
                                                   const float* __restrict__ dinv, const float* __restrict__ h,
                                                   const float* __restrict__ h0, float* __restrict__ out) {
  int r = blockIdx.x;
  int f = threadIdx.x;
  int m = r / NN, rem = r % NN;
  int d = rem / 100, i = rem % 100;
  int b = m * DD + d;
  __shared__ float av[100];
  if (f < 100) av[f] = blocks[(size_t)b * 10000 + i * 100 + f];
  __syncthreads();
  float acc = 0.0f;
  int cb = (b * 100) * 256;
  for (int j = 0; j < 100; ++j) {
    float a = av[j];
    if (a != 0.0f) acc += a * h[cb + j * 256 + f];
  }
  float dr = dinv[r];
  const float *a1, *a2; int n1, n2;
  if (m == 0)      { a1 = c01; a2 = c02; n1 = 1; n2 = 2; }
  else if (m == 1) { a1 = c01; a2 = c12; n1 = 0; n2 = 2; }
  else             { a1 = c02; a2 = c12; n1 = 0; n2 = 1; }
  acc += a1[rem] * dr * dinv[n1 * NN + rem] * h[((size_t)n1 * NN + rem) * 256 + f];
  acc += a2[rem] * dr * dinv[n2 * NN + rem] * h[((size_t)n2 * NN + rem) * 256 + f];
  out[(size_t)r * 256 + f] = 0.9f * acc + 0.1f * h0[(size_t)r * 256 + f];
}

// features_e[:, 256:512] = h2
__global__ __launch_bounds__(256) void outh_kernel(const float* __restrict__ h, float* __restrict__ fe) {
  int r = blockIdx.x, f = threadIdx.x;
  fe[(size_t)r * 512 + 256 + f] = h[(size_t)r * 256 + f];
}

// neighbor_emb + ft/fv/fp from features_e
__global__ __launch_bounds__(256) void outcopy_kernel(const float* __restrict__ fe, float* __restrict__ out) {
  int p = blockIdx.x * 256 + threadIdx.x;  // 0 .. 4,608,000
  if (p >= 4608000) return;
  int m = p / 1536000;
  int rest = p % 1536000;
  int rem = rest / 512, cc = rest % 512;
  float val = fe[(size_t)(m * NN + rem) * 512 + cc];
  out[OF_NB + (size_t)rem * 1536 + m * 512 + cc] = val;
  out[OF_FT + (size_t)p] = val;
}

extern "C" void kernel_launch(void* const* d_in, const int* in_sizes, int n_in,
                              void* d_out, int out_size, void* d_ws, size_t ws_size,
                              hipStream_t stream) {
  const float* t  = (const float*)d_in[0];
  const float* v  = (const float*)d_in[1];
  const float* p  = (const float*)d_in[2];
  const float* W0 = (const float*)d_in[3];
  const float* b0 = (const float*)d_in[4];
  const float* Ws = (const float*)d_in[5];
  float* out = (float*)d_out;
  float* ws  = (float*)d_ws;

  float* blocks = ws + WS_BLOCKS;
  float* c01 = ws + WS_C01;
  float* c02 = ws + WS_C02;
  float* c12 = ws + WS_C12;
  float* dinv = ws + WS_DINV;

  float* adj    = out + OF_ADJ;
  float* normed = out + OF_ADJ;            // scratch inside adj region, consumed before memset
  float* fe     = out + OF_FE;
  float* h0     = out + OF_NB;             // scratch inside neighbor_emb region
  float* h1     = out + OF_NB + 2304000;
  float* h2     = out + OF_NB;             // reuses h0 slot (h0 dead by then)
  float* tmp    = out + OF_FT;             // scratch inside ft/fv/fp region

  fillx_kernel<<<9000, 256, 0, stream>>>(t, v, p, fe);
  norm_kernel<<<9000, 64, 0, stream>>>(t, v, p, normed);
  spital_kernel<<<90, 256, 0, stream>>>(normed, blocks);
  dsim_kernel<<<3000, 64, 0, stream>>>(normed, c01, c02, c12);
  sparsify_kernel<<<90, 128, 0, stream>>>(blocks);
  deg_kernel<<<36, 256, 0, stream>>>(blocks, c01, c02, c12, dinv);
  normblocks_kernel<<<3516, 256, 0, stream>>>(blocks, dinv);
  hipMemsetAsync(adj, 0, (size_t)81000000 * sizeof(float), stream);
  scatter_kernel<<<90, 256, 0, stream>>>(blocks, c01, c02, c12, dinv, adj);

  // GCNII
  gemm_kernel<<<141 * 4, 256, 0, stream>>>(fe, 512, W0, b0, h0, 9000, 0, 0.f, 0.f);
  spmm_kernel<<<9000, 256, 0, stream>>>(blocks, c01, c02, c12, dinv, h0, h0, tmp);
  gemm_kernel<<<141 * 4, 256, 0, stream>>>(tmp, 256, Ws, nullptr, h1, 9000, 1,
                                           0.4054651081081644f, 0.5945348918918356f);
  spmm_kernel<<<9000, 256, 0, stream>>>(blocks, c01, c02, c12, dinv, h1, h0, tmp);
  gemm_kernel<<<141 * 4, 256, 0, stream>>>(tmp, 256, Ws + 65536, nullptr, h2, 9000, 1,
                                           0.22314355131420976f, 0.7768564486857902f);

  outh_kernel<<<9000, 256, 0, stream>>>(h2, fe);
  outcopy_kernel<<<18000, 256, 0, stream>>>(fe, out);
}

// Round 2
// 590.542 us; speedup vs baseline: 1.5980x; 1.5980x over previous
//
#include <hip/hip_runtime.h>
#include <math.h>

#define NN 3000
#define DD 30
#define LLEN 100
#define NDIM 256
#define PI_F 3.14159265358979323846f

// ---- output layout (float offsets) ----
#define OF_FE  0          // features_e: 9000 x 512
#define OF_ADJ 4608000    // adj_la: 9000 x 9000
#define OF_NB  85608000   // neighbor_emb: 3000 x 1536
#define OF_FT  90216000   // ft|fv|fp: 3 x (3000 x 512)

// ---- workspace layout (float offsets) ----
#define WS_BLOCKS 0       // 90 * 100 * 100
#define WS_C01 900000
#define WS_C02 903000
#define WS_C12 906000
#define WS_DINV 909000    // 9000

__device__ __forceinline__ const float* xrow(int r, const float* t, const float* v, const float* p) {
  if (r < NN) return t + (size_t)r * NDIM;
  if (r < 2*NN) return v + (size_t)(r - NN) * NDIM;
  return p + (size_t)(r - 2*NN) * NDIM;
}

// features_e[:, 0:256] = X
__global__ __launch_bounds__(256) void fillx_kernel(const float* __restrict__ t, const float* __restrict__ v,
                                                    const float* __restrict__ p, float* __restrict__ fe) {
  int r = blockIdx.x, f = threadIdx.x;
  fe[(size_t)r * 512 + f] = xrow(r, t, v, p)[f];
}

// row-normalize all 9000 feature rows
__global__ __launch_bounds__(64) void norm_kernel(const float* __restrict__ t, const float* __restrict__ v,
                                                  const float* __restrict__ p, float* __restrict__ normed) {
  int r = blockIdx.x, lane = threadIdx.x;
  const float* src = xrow(r, t, v, p);
  float4 x = ((const float4*)src)[lane];
  float ss = x.x*x.x + x.y*x.y + x.z*x.z + x.w*x.w;
  #pragma unroll
  for (int off = 32; off > 0; off >>= 1) ss += __shfl_xor(ss, off);
  float nrm = sqrtf(ss);
  float4 o = make_float4(x.x/nrm, x.y/nrm, x.z/nrm, x.w/nrm);
  ((float4*)(normed + (size_t)r * NDIM))[lane] = o;
}

// per (m,d): spital[i][j] = (1 - acos(dot_ij*0.99999)/pi) / (log(|i-j|+1)+1e-4)
#define LPAD 112
__global__ __launch_bounds__(256) void spital_kernel(const float* __restrict__ normed, float* __restrict__ blocks) {
  int b = blockIdx.x;          // m*30+d ; node base = b*100
  int base = b * 100;
  __shared__ float Ts[64][LPAD];
  int tid = threadIdx.x;
  int tn = tid & 15, tm = tid >> 4;
  float acc[7][7];
  #pragma unroll
  for (int q = 0; q < 7; ++q)
    #pragma unroll
    for (int s = 0; s < 7; ++s) acc[q][s] = 0.0f;

  for (int kk = 0; kk < 256; kk += 64) {
    for (int pp = tid; pp < 100 * 16; pp += 256) {
      int kq = pp & 15, i = pp >> 4;
      float4 vv = *(const float4*)&normed[(size_t)(base + i) * NDIM + kk + kq * 4];
      Ts[kq*4+0][i] = vv.x; Ts[kq*4+1][i] = vv.y; Ts[kq*4+2][i] = vv.z; Ts[kq*4+3][i] = vv.w;
    }
    __syncthreads();
    #pragma unroll 4
    for (int k = 0; k < 64; ++k) {
      float a[7], bb[7];
      #pragma unroll
      for (int q = 0; q < 7; ++q) { int i = tm*7+q; if (i > 99) i = 99; a[q] = Ts[k][i]; }
      #pragma unroll
      for (int s = 0; s < 7; ++s) { int j = tn*7+s; if (j > 99) j = 99; bb[s] = Ts[k][j]; }
      #pragma unroll
      for (int q = 0; q < 7; ++q)
        #pragma unroll
        for (int s = 0; s < 7; ++s) acc[q][s] += a[q] * bb[s];
    }
    __syncthreads();
  }
  #pragma unroll
  for (int q = 0; q < 7; ++q) {
    int i = tm*7+q; if (i >= 100) continue;
    #pragma unroll
    for (int s = 0; s < 7; ++s) {
      int j = tn*7+s; if (j >= 100) continue;
      float S = acc[q][s] * 0.99999f;
      float sim = 1.0f - acosf(S) / PI_F;
      int dd = i - j; if (dd < 0) dd = -dd;
      float decay = logf((float)dd + 1.0f) + 1e-4f;
      blocks[(size_t)b * 10000 + i * 100 + j] = sim / decay;
    }
  }
}

// cross-modality diagonal sims
__global__ __launch_bounds__(64) void dsim_kernel(const float* __restrict__ normed, float* __restrict__ c01,
                                                  float* __restrict__ c02, float* __restrict__ c12) {
  int rem = blockIdx.x, lane = threadIdx.x;
  float4 a = ((const float4*)&normed[(size_t)rem * NDIM])[lane];
  float4 b = ((const float4*)&normed[(size_t)(NN + rem) * NDIM])[lane];
  float4 c = ((const float4*)&normed[(size_t)(2*NN + rem) * NDIM])[lane];
  float s01 = a.x*b.x + a.y*b.y + a.z*b.z + a.w*b.w;
  float s02 = a.x*c.x + a.y*c.y + a.z*c.z + a.w*c.w;
  float s12 = b.x*c.x + b.y*c.y + b.z*c.z + b.w*c.w;
  #pragma unroll
  for (int off = 32; off > 0; off >>= 1) {
    s01 += __shfl_xor(s01, off);
    s02 += __shfl_xor(s02, off);
    s12 += __shfl_xor(s12, off);
  }
  if (lane == 0) {
    c01[rem] = 1.0f - acosf(s01 * 0.99999f) / PI_F;
    c02[rem] = 1.0f - acosf(s02 * 0.99999f) / PI_F;
    c12[rem] = 1.0f - acosf(s12 * 0.99999f) / PI_F;
  }
}

// sequential scan: for e in 0..99 { zero 80 smallest of col e; then of row e }
// Branch-free count: for vi>0 (generically distinct positives), stable rank
// = #(vj < vi); zeros tie only with zeros and re-zeroing is a no-op.
// A rows padded to 101 floats (coprime with 32 banks -> conflict-free
// strided column access).
#define APAD 101
__global__ __launch_bounds__(128) void sparsify_kernel(float* __restrict__ blocks) {
  int b = blockIdx.x;
  __shared__ float A[100 * APAD];
  __shared__ float colbuf[104];
  int tid = threadIdx.x;
  for (int p0 = tid; p0 < 10000; p0 += 128) {
    int i = p0 / 100, j = p0 % 100;
    A[i * APAD + j] = blocks[(size_t)b * 10000 + p0];
  }
  if (tid >= 100 && tid < 104) colbuf[tid] = 3.0e38f;  // pad: never < vi
  __syncthreads();

  for (int e = 0; e < 100; ++e) {
    // ---- column phase ----
    if (tid < 100) colbuf[tid] = A[tid * APAD + e];
    __syncthreads();
    if (tid < 100) {
      float vi = colbuf[tid];
      int cnt = 0;
      #pragma unroll
      for (int q = 0; q < 26; ++q) {
        float4 vj = *(const float4*)&colbuf[q * 4];
        cnt += (int)(vj.x < vi) + (int)(vj.y < vi) + (int)(vj.z < vi) + (int)(vj.w < vi);
      }
      if (cnt < 80 && vi != 0.0f) A[tid * APAD + e] = 0.0f;
    }
    __syncthreads();
    // ---- row phase ----
    if (tid < 100) colbuf[tid] = A[e * APAD + tid];
    __syncthreads();
    if (tid < 100) {
      float vi = colbuf[tid];
      int cnt = 0;
      #pragma unroll
      for (int q = 0; q < 26; ++q) {
        float4 vj = *(const float4*)&colbuf[q * 4];
        cnt += (int)(vj.x < vi) + (int)(vj.y < vi) + (int)(vj.z < vi) + (int)(vj.w < vi);
      }
      if (cnt < 80 && vi != 0.0f) A[e * APAD + tid] = 0.0f;
    }
    __syncthreads();
  }
  for (int p0 = tid; p0 < 10000; p0 += 128) {
    int i = p0 / 100, j = p0 % 100;
    blocks[(size_t)b * 10000 + p0] = A[i * APAD + j];
  }
}

// degree -> dinv
__global__ __launch_bounds__(256) void deg_kernel(const float* __restrict__ blocks, const float* __restrict__ c01,
                                                  const float* __restrict__ c02, const float* __restrict__ c12,
                                                  float* __restrict__ dinv) {
  int r = blockIdx.x * 256 + threadIdx.x;
  if (r >= 3*NN) return;
  int m = r / NN, rem = r % NN;
  int d = rem / 100, i = rem % 100;
  const float* row = &blocks[((size_t)(m*DD + d)) * 10000 + i * 100];
  float s = 0.0f;
  for (int j = 0; j < 100; ++j) s += row[j];
  if (m == 0) s += c01[rem] + c02[rem];
  else if (m == 1) s += c01[rem] + c12[rem];
  else s += c02[rem] + c12[rem];
  if (s == 0.0f) s = 1e-12f;
  dinv[r] = 1.0f / sqrtf(s);
}

// blocks *= dinv_r * dinv_c (in place)
__global__ __launch_bounds__(256) void normblocks_kernel(float* __restrict__ blocks, const float* __restrict__ dinv) {
  int p = blockIdx.x * 256 + threadIdx.x;
  if (p >= 900000) return;
  int b = p / 10000, q = p % 10000;
  int i = q / 100, j = q % 100;
  int rbase = b * 100;
  blocks[p] *= dinv[rbase + i] * dinv[rbase + j];
}

// scatter normalized blocks + cross entries into dense adj (pre-zeroed)
__global__ __launch_bounds__(256) void scatter_kernel(const float* __restrict__ blocks, const float* __restrict__ c01,
                                                      const float* __restrict__ c02, const float* __restrict__ c12,
                                                      const float* __restrict__ dinv, float* __restrict__ adj) {
  int b = blockIdx.x, m = b / DD, d = b % DD;
  int rbase = b * 100;
  for (int p = threadIdx.x; p < 10000; p += 256) {
    int i = p / 100, j = p % 100;
    adj[(size_t)(rbase + i) * 9000 + rbase + j] = blocks[(size_t)b * 10000 + p];
  }
  int tid = threadIdx.x;
  if (tid < 100) {
    int rem = d * 100 + tid;
    int r = rbase + tid;
    float dr = dinv[r];
    const float *a1, *a2; int n1, n2;
    if (m == 0)      { a1 = c01; a2 = c02; n1 = 1; n2 = 2; }
    else if (m == 1) { a1 = c01; a2 = c12; n1 = 0; n2 = 2; }
    else             { a1 = c02; a2 = c12; n1 = 0; n2 = 1; }
    adj[(size_t)r * 9000 + n1 * NN + rem] = a1[rem] * dr * dinv[n1 * NN + rem];
    adj[(size_t)r * 9000 + n2 * NN + rem] = a2[rem] * dr * dinv[n2 * NN + rem];
  }
}

// C = relu(A@W + bias)            (mode 0)
// C = relu(theta*(A@W) + omtheta*A) (mode 1, N==K==256)
__global__ __launch_bounds__(256) void gemm_kernel(const float* __restrict__ A, int lda,
                                                   const float* __restrict__ W, const float* __restrict__ bias,
                                                   float* __restrict__ C, int M, int mode,
                                                   float theta, float omtheta) {
  __shared__ float As[16][64];
  __shared__ float Bs[16][64];
  int bx = blockIdx.x & 3;
  int by = blockIdx.x >> 2;
  int tid = threadIdx.x;
  int tn = tid & 15, tm = tid >> 4;
  int row0 = by * 64, col0 = bx * 64;
  float acc[4][4];
  #pragma unroll
  for (int i = 0; i < 4; ++i)
    #pragma unroll
    for (int j = 0; j < 4; ++j) acc[i][j] = 0.0f;
  int lr = tid >> 2, lc = tid & 3;
  int br = tid >> 4, bc = tid & 15;

  for (int kk = 0; kk < 256; kk += 16) {
    int ar = row0 + lr;
    float4 av = make_float4(0.f, 0.f, 0.f, 0.f);
    if (ar < M) av = *(const float4*)&A[(size_t)ar * lda + kk + lc * 4];
    As[lc*4+0][lr] = av.x; As[lc*4+1][lr] = av.y; As[lc*4+2][lr] = av.z; As[lc*4+3][lr] = av.w;
    *(float4*)&Bs[br][bc * 4] = *(const float4*)&W[(size_t)(kk + br) * 256 + col0 + bc * 4];
    __syncthreads();
    #pragma unroll
    for (int k = 0; k < 16; ++k) {
      float4 a4 = *(const float4*)&As[k][tm * 4];
      float4 b4 = *(const float4*)&Bs[k][tn * 4];
      float a[4] = {a4.x, a4.y, a4.z, a4.w};
      float bb[4] = {b4.x, b4.y, b4.z, b4.w};
      #pragma unroll
      for (int ii = 0; ii < 4; ++ii)
        #pragma unroll
        for (int jj = 0; jj < 4; ++jj) acc[ii][jj] += a[ii] * bb[jj];
    }
    __syncthreads();
  }
  #pragma unroll
  for (int ii = 0; ii < 4; ++ii) {
    int r = row0 + tm * 4 + ii;
    if (r >= M) continue;
    #pragma unroll
    for (int jj = 0; jj < 4; ++jj) {
      int c = col0 + tn * 4 + jj;
      float val = acc[ii][jj];
      if (mode == 0) val += bias[c];
      else val = theta * val + omtheta * A[(size_t)r * lda + c];
      C[(size_t)r * 256 + c] = fmaxf(val, 0.0f);
    }
  }
}

// support = 0.9 * (adj_norm @ h) + 0.1 * h0   (block-sparse adj)
__global__ __launch_bounds__(256) void spmm_kernel(const float* __restrict__ blocks, const float* __restrict__ c01,
                                                   const float* __restrict__ c02, const float* __restrict__ c12,
                                                   const float* __restrict__ dinv, const float* __restrict__ h,
                                                   const float* __restrict__ h0, float* __restrict__ out) {
  int r = blockIdx.x;
  int f = threadIdx.x;
  int m = r / NN, rem = r % NN;
  int d = rem / 100, i = rem % 100;
  int b = m * DD + d;
  __shared__ float av[100];
  if (f < 100) av[f] = blocks[(size_t)b * 10000 + i * 100 + f];
  __syncthreads();
  float acc = 0.0f;
  int cb = (b * 100) * 256;
  for (int j = 0; j < 100; ++j) {
    float a = av[j];
    if (a != 0.0f) acc += a * h[cb + j * 256 + f];
  }
  float dr = dinv[r];
  const float *a1, *a2; int n1, n2;
  if (m == 0)      { a1 = c01; a2 = c02; n1 = 1; n2 = 2; }
  else if (m == 1) { a1 = c01; a2 = c12; n1 = 0; n2 = 2; }
  else             { a1 = c02; a2 = c12; n1 = 0; n2 = 1; }
  acc += a1[rem] * dr * dinv[n1 * NN + rem] * h[((size_t)n1 * NN + rem) * 256 + f];
  acc += a2[rem] * dr * dinv[n2 * NN + rem] * h[((size_t)n2 * NN + rem) * 256 + f];
  out[(size_t)r * 256 + f] = 0.9f * acc + 0.1f * h0[(size_t)r * 256 + f];
}

// features_e[:, 256:512] = h2
__global__ __launch_bounds__(256) void outh_kernel(const float* __restrict__ h, float* __restrict__ fe) {
  int r = blockIdx.x, f = threadIdx.x;
  fe[(size_t)r * 512 + 256 + f] = h[(size_t)r * 256 + f];
}

// neighbor_emb + ft/fv/fp from features_e
__global__ __launch_bounds__(256) void outcopy_kernel(const float* __restrict__ fe, float* __restrict__ out) {
  int p = blockIdx.x * 256 + threadIdx.x;  // 0 .. 4,608,000
  if (p >= 4608000) return;
  int m = p / 1536000;
  int rest = p % 1536000;
  int rem = rest / 512, cc = rest % 512;
  float val = fe[(size_t)(m * NN + rem) * 512 + cc];
  out[OF_NB + (size_t)rem * 1536 + m * 512 + cc] = val;
  out[OF_FT + (size_t)p] = val;
}

extern "C" void kernel_launch(void* const* d_in, const int* in_sizes, int n_in,
                              void* d_out, int out_size, void* d_ws, size_t ws_size,
                              hipStream_t stream) {
  const float* t  = (const float*)d_in[0];
  const float* v  = (const float*)d_in[1];
  const float* p  = (const float*)d_in[2];
  const float* W0 = (const float*)d_in[3];
  const float* b0 = (const float*)d_in[4];
  const float* Ws = (const float*)d_in[5];
  float* out = (float*)d_out;
  float* ws  = (float*)d_ws;

  float* blocks = ws + WS_BLOCKS;
  float* c01 = ws + WS_C01;
  float* c02 = ws + WS_C02;
  float* c12 = ws + WS_C12;
  float* dinv = ws + WS_DINV;

  float* adj    = out + OF_ADJ;
  float* normed = out + OF_ADJ;            // scratch inside adj region, consumed before memset
  float* fe     = out + OF_FE;
  float* h0     = out + OF_NB;             // scratch inside neighbor_emb region
  float* h1     = out + OF_NB + 2304000;
  float* h2     = out + OF_NB;             // reuses h0 slot (h0 dead by then)
  float* tmp    = out + OF_FT;             // scratch inside ft/fv/fp region

  fillx_kernel<<<9000, 256, 0, stream>>>(t, v, p, fe);
  norm_kernel<<<9000, 64, 0, stream>>>(t, v, p, normed);
  spital_kernel<<<90, 256, 0, stream>>>(normed, blocks);
  dsim_kernel<<<3000, 64, 0, stream>>>(normed, c01, c02, c12);
  sparsify_kernel<<<90, 128, 0, stream>>>(blocks);
  deg_kernel<<<36, 256, 0, stream>>>(blocks, c01, c02, c12, dinv);
  normblocks_kernel<<<3516, 256, 0, stream>>>(blocks, dinv);
  hipMemsetAsync(adj, 0, (size_t)81000000 * sizeof(float), stream);
  scatter_kernel<<<90, 256, 0, stream>>>(blocks, c01, c02, c12, dinv, adj);

  // GCNII
  gemm_kernel<<<141 * 4, 256, 0, stream>>>(fe, 512, W0, b0, h0, 9000, 0, 0.f, 0.f);
  spmm_kernel<<<9000, 256, 0, stream>>>(blocks, c01, c02, c12, dinv, h0, h0, tmp);
  gemm_kernel<<<141 * 4, 256, 0, stream>>>(tmp, 256, Ws, nullptr, h1, 9000, 1,
                                           0.4054651081081644f, 0.5945348918918356f);
  spmm_kernel<<<9000, 256, 0, stream>>>(blocks, c01, c02, c12, dinv, h1, h0, tmp);
  gemm_kernel<<<141 * 4, 256, 0, stream>>>(tmp, 256, Ws + 65536, nullptr, h2, 9000, 1,
                                           0.22314355131420976f, 0.7768564486857902f);

  outh_kernel<<<9000, 256, 0, stream>>>(h2, fe);
  outcopy_kernel<<<18000, 256, 0, stream>>>(fe, out);
}

// Round 3
// 559.719 us; speedup vs baseline: 1.6860x; 1.0551x over previous
//
#include <hip/hip_runtime.h>
#include <math.h>

#define NN 3000
#define DD 30
#define LLEN 100
#define NDIM 256
#define PI_F 3.14159265358979323846f

// ---- output layout (float offsets) ----
#define OF_FE  0          // features_e: 9000 x 512
#define OF_ADJ 4608000    // adj_la: 9000 x 9000
#define OF_NB  85608000   // neighbor_emb: 3000 x 1536
#define OF_FT  90216000   // ft|fv|fp: 3 x (3000 x 512)

// ---- workspace layout (float offsets) ----
#define WS_BLOCKS 0       // 90 * 100 * 100
#define WS_C01 900000
#define WS_C02 903000
#define WS_C12 906000
#define WS_DINV 909000    // 9000

__device__ __forceinline__ const float* xrow(int r, const float* t, const float* v, const float* p) {
  if (r < NN) return t + (size_t)r * NDIM;
  if (r < 2*NN) return v + (size_t)(r - NN) * NDIM;
  return p + (size_t)(r - 2*NN) * NDIM;
}

// features_e[:, 0:256] = X
__global__ __launch_bounds__(256) void fillx_kernel(const float* __restrict__ t, const float* __restrict__ v,
                                                    const float* __restrict__ p, float* __restrict__ fe) {
  int r = blockIdx.x, f = threadIdx.x;
  fe[(size_t)r * 512 + f] = xrow(r, t, v, p)[f];
}

// row-normalize all 9000 feature rows
__global__ __launch_bounds__(64) void norm_kernel(const float* __restrict__ t, const float* __restrict__ v,
                                                  const float* __restrict__ p, float* __restrict__ normed) {
  int r = blockIdx.x, lane = threadIdx.x;
  const float* src = xrow(r, t, v, p);
  float4 x = ((const float4*)src)[lane];
  float ss = x.x*x.x + x.y*x.y + x.z*x.z + x.w*x.w;
  #pragma unroll
  for (int off = 32; off > 0; off >>= 1) ss += __shfl_xor(ss, off);
  float nrm = sqrtf(ss);
  float4 o = make_float4(x.x/nrm, x.y/nrm, x.z/nrm, x.w/nrm);
  ((float4*)(normed + (size_t)r * NDIM))[lane] = o;
}

// per (m,d): spital[i][j] = (1 - acos(dot_ij*0.99999)/pi) / (log(|i-j|+1)+1e-4)
#define LPAD 112
__global__ __launch_bounds__(256) void spital_kernel(const float* __restrict__ normed, float* __restrict__ blocks) {
  int b = blockIdx.x;          // m*30+d ; node base = b*100
  int base = b * 100;
  __shared__ float Ts[64][LPAD];
  int tid = threadIdx.x;
  int tn = tid & 15, tm = tid >> 4;
  float acc[7][7];
  #pragma unroll
  for (int q = 0; q < 7; ++q)
    #pragma unroll
    for (int s = 0; s < 7; ++s) acc[q][s] = 0.0f;

  for (int kk = 0; kk < 256; kk += 64) {
    for (int pp = tid; pp < 100 * 16; pp += 256) {
      int kq = pp & 15, i = pp >> 4;
      float4 vv = *(const float4*)&normed[(size_t)(base + i) * NDIM + kk + kq * 4];
      Ts[kq*4+0][i] = vv.x; Ts[kq*4+1][i] = vv.y; Ts[kq*4+2][i] = vv.z; Ts[kq*4+3][i] = vv.w;
    }
    __syncthreads();
    #pragma unroll 4
    for (int k = 0; k < 64; ++k) {
      float a[7], bb[7];
      #pragma unroll
      for (int q = 0; q < 7; ++q) { int i = tm*7+q; if (i > 99) i = 99; a[q] = Ts[k][i]; }
      #pragma unroll
      for (int s = 0; s < 7; ++s) { int j = tn*7+s; if (j > 99) j = 99; bb[s] = Ts[k][j]; }
      #pragma unroll
      for (int q = 0; q < 7; ++q)
        #pragma unroll
        for (int s = 0; s < 7; ++s) acc[q][s] += a[q] * bb[s];
    }
    __syncthreads();
  }
  #pragma unroll
  for (int q = 0; q < 7; ++q) {
    int i = tm*7+q; if (i >= 100) continue;
    #pragma unroll
    for (int s = 0; s < 7; ++s) {
      int j = tn*7+s; if (j >= 100) continue;
      float S = acc[q][s] * 0.99999f;
      float sim = 1.0f - acosf(S) / PI_F;
      int dd = i - j; if (dd < 0) dd = -dd;
      float decay = logf((float)dd + 1.0f) + 1e-4f;
      blocks[(size_t)b * 10000 + i * 100 + j] = sim / decay;
    }
  }
}

// cross-modality diagonal sims
__global__ __launch_bounds__(64) void dsim_kernel(const float* __restrict__ normed, float* __restrict__ c01,
                                                  float* __restrict__ c02, float* __restrict__ c12) {
  int rem = blockIdx.x, lane = threadIdx.x;
  float4 a = ((const float4*)&normed[(size_t)rem * NDIM])[lane];
  float4 b = ((const float4*)&normed[(size_t)(NN + rem) * NDIM])[lane];
  float4 c = ((const float4*)&normed[(size_t)(2*NN + rem) * NDIM])[lane];
  float s01 = a.x*b.x + a.y*b.y + a.z*b.z + a.w*b.w;
  float s02 = a.x*c.x + a.y*c.y + a.z*c.z + a.w*c.w;
  float s12 = b.x*c.x + b.y*c.y + b.z*c.z + b.w*c.w;
  #pragma unroll
  for (int off = 32; off > 0; off >>= 1) {
    s01 += __shfl_xor(s01, off);
    s02 += __shfl_xor(s02, off);
    s12 += __shfl_xor(s12, off);
  }
  if (lane == 0) {
    c01[rem] = 1.0f - acosf(s01 * 0.99999f) / PI_F;
    c02[rem] = 1.0f - acosf(s02 * 0.99999f) / PI_F;
    c12[rem] = 1.0f - acosf(s12 * 0.99999f) / PI_F;
  }
}

// Sequential top-K scan, merged col+row step.
// Reference: step e = {zero 80 smallest of col e; then of row e}.
// Col-phase e only modifies row e at A[e][e] (the diagonal, ~sim/1e-4 ~ 1e4,
// strict column max -> rank 99 -> never zeroed), so row-ranks of step e can
// be computed concurrently with col-ranks from the post-step-(e-1) state.
// A and AT both kept in LDS so all count reads are contiguous float4
// broadcasts (all lanes same address -> conflict-free).
// Branch-free stable rank for vi>0: cnt = #(vj < vi)  (zeros only tie with
// zeros; re-zeroing a zero is a no-op -> skipped via vi!=0).
#define AROW 100
__global__ __launch_bounds__(128) void sparsify_kernel(float* __restrict__ blocks) {
  int b = blockIdx.x;
  __shared__ float A [100 * AROW];   // row-major
  __shared__ float AT[100 * AROW];   // transpose
  int tid = threadIdx.x;
  for (int p0 = tid; p0 < 10000; p0 += 128) {
    int i = p0 / 100, j = p0 % 100;
    float val = blocks[(size_t)b * 10000 + p0];
    A [i * AROW + j] = val;
    AT[j * AROW + i] = val;
  }
  __syncthreads();

  for (int e = 0; e < 100; ++e) {
    float vc = 0.f, vr = 0.f;
    int cc = 0, cr = 0;
    if (tid < 100) {
      vc = AT[e * AROW + tid];   // column e, element tid
      vr = A [e * AROW + tid];   // row e, element tid
      #pragma unroll
      for (int q = 0; q < 25; ++q) {
        float4 c4 = *(const float4*)&AT[e * AROW + q * 4];
        float4 r4 = *(const float4*)&A [e * AROW + q * 4];
        cc += (int)(c4.x < vc) + (int)(c4.y < vc) + (int)(c4.z < vc) + (int)(c4.w < vc);
        cr += (int)(r4.x < vr) + (int)(r4.y < vr) + (int)(r4.z < vr) + (int)(r4.w < vr);
      }
    }
    __syncthreads();
    if (tid < 100) {
      if (cc < 80 && vc != 0.0f) { A[tid * AROW + e] = 0.0f; AT[e * AROW + tid] = 0.0f; }
      if (cr < 80 && vr != 0.0f) { A[e * AROW + tid] = 0.0f; AT[tid * AROW + e] = 0.0f; }
    }
    __syncthreads();
  }
  for (int p0 = tid; p0 < 10000; p0 += 128)
    blocks[(size_t)b * 10000 + p0] = A[p0];
}

// degree -> dinv
__global__ __launch_bounds__(256) void deg_kernel(const float* __restrict__ blocks, const float* __restrict__ c01,
                                                  const float* __restrict__ c02, const float* __restrict__ c12,
                                                  float* __restrict__ dinv) {
  int r = blockIdx.x * 256 + threadIdx.x;
  if (r >= 3*NN) return;
  int m = r / NN, rem = r % NN;
  int d = rem / 100, i = rem % 100;
  const float* row = &blocks[((size_t)(m*DD + d)) * 10000 + i * 100];
  float s = 0.0f;
  for (int j = 0; j < 100; ++j) s += row[j];
  if (m == 0) s += c01[rem] + c02[rem];
  else if (m == 1) s += c01[rem] + c12[rem];
  else s += c02[rem] + c12[rem];
  if (s == 0.0f) s = 1e-12f;
  dinv[r] = 1.0f / sqrtf(s);
}

// blocks *= dinv_r * dinv_c (in place)
__global__ __launch_bounds__(256) void normblocks_kernel(float* __restrict__ blocks, const float* __restrict__ dinv) {
  int p = blockIdx.x * 256 + threadIdx.x;
  if (p >= 900000) return;
  int b = p / 10000, q = p % 10000;
  int i = q / 100, j = q % 100;
  int rbase = b * 100;
  blocks[p] *= dinv[rbase + i] * dinv[rbase + j];
}

// one block per adjacency row: zeros + diag-block segment + 2 cross entries
__global__ __launch_bounds__(256) void adjwrite_kernel(const float* __restrict__ blocks, const float* __restrict__ c01,
                                                       const float* __restrict__ c02, const float* __restrict__ c12,
                                                       const float* __restrict__ dinv, float* __restrict__ adj) {
  int r = blockIdx.x;
  int m = r / NN, rem = r % NN;
  int d = rem / 100, i = rem % 100;
  int bb = m * DD + d;
  int rbase = bb * 100;
  float* row = adj + (size_t)r * 9000;
  float4 z = make_float4(0.f, 0.f, 0.f, 0.f);
  for (int c4 = threadIdx.x; c4 < 2250; c4 += 256) ((float4*)row)[c4] = z;
  __syncthreads();
  int tid = threadIdx.x;
  if (tid < 100)
    row[rbase + tid] = blocks[(size_t)bb * 10000 + i * 100 + tid];
  if (tid == 0) {
    float dr = dinv[r];
    const float *a1, *a2; int n1, n2;
    if (m == 0)      { a1 = c01; a2 = c02; n1 = 1; n2 = 2; }
    else if (m == 1) { a1 = c01; a2 = c12; n1 = 0; n2 = 2; }
    else             { a1 = c02; a2 = c12; n1 = 0; n2 = 1; }
    row[n1 * NN + rem] = a1[rem] * dr * dinv[n1 * NN + rem];
    row[n2 * NN + rem] = a2[rem] * dr * dinv[n2 * NN + rem];
  }
}

// C = relu(A@W + bias)            (mode 0)
// C = relu(theta*(A@W) + omtheta*A) (mode 1, N==K==256)
__global__ __launch_bounds__(256) void gemm_kernel(const float* __restrict__ A, int lda,
                                                   const float* __restrict__ W, const float* __restrict__ bias,
                                                   float* __restrict__ C, int M, int mode,
                                                   float theta, float omtheta) {
  __shared__ float As[16][64];
  __shared__ float Bs[16][64];
  int bx = blockIdx.x & 3;
  int by = blockIdx.x >> 2;
  int tid = threadIdx.x;
  int tn = tid & 15, tm = tid >> 4;
  int row0 = by * 64, col0 = bx * 64;
  float acc[4][4];
  #pragma unroll
  for (int i = 0; i < 4; ++i)
    #pragma unroll
    for (int j = 0; j < 4; ++j) acc[i][j] = 0.0f;
  int lr = tid >> 2, lc = tid & 3;
  int br = tid >> 4, bc = tid & 15;

  for (int kk = 0; kk < 256; kk += 16) {
    int ar = row0 + lr;
    float4 av = make_float4(0.f, 0.f, 0.f, 0.f);
    if (ar < M) av = *(const float4*)&A[(size_t)ar * lda + kk + lc * 4];
    As[lc*4+0][lr] = av.x; As[lc*4+1][lr] = av.y; As[lc*4+2][lr] = av.z; As[lc*4+3][lr] = av.w;
    *(float4*)&Bs[br][bc * 4] = *(const float4*)&W[(size_t)(kk + br) * 256 + col0 + bc * 4];
    __syncthreads();
    #pragma unroll
    for (int k = 0; k < 16; ++k) {
      float4 a4 = *(const float4*)&As[k][tm * 4];
      float4 b4 = *(const float4*)&Bs[k][tn * 4];
      float a[4] = {a4.x, a4.y, a4.z, a4.w};
      float bb[4] = {b4.x, b4.y, b4.z, b4.w};
      #pragma unroll
      for (int ii = 0; ii < 4; ++ii)
        #pragma unroll
        for (int jj = 0; jj < 4; ++jj) acc[ii][jj] += a[ii] * bb[jj];
    }
    __syncthreads();
  }
  #pragma unroll
  for (int ii = 0; ii < 4; ++ii) {
    int r = row0 + tm * 4 + ii;
    if (r >= M) continue;
    #pragma unroll
    for (int jj = 0; jj < 4; ++jj) {
      int c = col0 + tn * 4 + jj;
      float val = acc[ii][jj];
      if (mode == 0) val += bias[c];
      else val = theta * val + omtheta * A[(size_t)r * lda + c];
      C[(size_t)r * 256 + c] = fmaxf(val, 0.0f);
    }
  }
}

// support = 0.9 * (adj_norm @ h) + 0.1 * h0   (block-sparse adj)
__global__ __launch_bounds__(256) void spmm_kernel(const float* __restrict__ blocks, const float* __restrict__ c01,
                                                   const float* __restrict__ c02, const float* __restrict__ c12,
                                                   const float* __restrict__ dinv, const float* __restrict__ h,
                                                   const float* __restrict__ h0, float* __restrict__ out) {
  int r = blockIdx.x;
  int f = threadIdx.x;
  int m = r / NN, rem = r % NN;
  int d = rem / 100, i = rem % 100;
  int b = m * DD + d;
  __shared__ float av[100];
  if (f < 100) av[f] = blocks[(size_t)b * 10000 + i * 100 + f];
  __syncthreads();
  float acc = 0.0f;
  int cb = (b * 100) * 256;
  for (int j = 0; j < 100; ++j) {
    float a = av[j];
    if (a != 0.0f) acc += a * h[cb + j * 256 + f];
  }
  float dr = dinv[r];
  const float *a1, *a2; int n1, n2;
  if (m == 0)      { a1 = c01; a2 = c02; n1 = 1; n2 = 2; }
  else if (m == 1) { a1 = c01; a2 = c12; n1 = 0; n2 = 2; }
  else             { a1 = c02; a2 = c12; n1 = 0; n2 = 1; }
  acc += a1[rem] * dr * dinv[n1 * NN + rem] * h[((size_t)n1 * NN + rem) * 256 + f];
  acc += a2[rem] * dr * dinv[n2 * NN + rem] * h[((size_t)n2 * NN + rem) * 256 + f];
  out[(size_t)r * 256 + f] = 0.9f * acc + 0.1f * h0[(size_t)r * 256 + f];
}

// features_e[:, 256:512] = h2
__global__ __launch_bounds__(256) void outh_kernel(const float* __restrict__ h, float* __restrict__ fe) {
  int r = blockIdx.x, f = threadIdx.x;
  fe[(size_t)r * 512 + 256 + f] = h[(size_t)r * 256 + f];
}

// neighbor_emb + ft/fv/fp from features_e
__global__ __launch_bounds__(256) void outcopy_kernel(const float* __restrict__ fe, float* __restrict__ out) {
  int p = blockIdx.x * 256 + threadIdx.x;  // 0 .. 4,608,000
  if (p >= 4608000) return;
  int m = p / 1536000;
  int rest = p % 1536000;
  int rem = rest / 512, cc = rest % 512;
  float val = fe[(size_t)(m * NN + rem) * 512 + cc];
  out[OF_NB + (size_t)rem * 1536 + m * 512 + cc] = val;
  out[OF_FT + (size_t)p] = val;
}

extern "C" void kernel_launch(void* const* d_in, const int* in_sizes, int n_in,
                              void* d_out, int out_size, void* d_ws, size_t ws_size,
                              hipStream_t stream) {
  const float* t  = (const float*)d_in[0];
  const float* v  = (const float*)d_in[1];
  const float* p  = (const float*)d_in[2];
  const float* W0 = (const float*)d_in[3];
  const float* b0 = (const float*)d_in[4];
  const float* Ws = (const float*)d_in[5];
  float* out = (float*)d_out;
  float* ws  = (float*)d_ws;

  float* blocks = ws + WS_BLOCKS;
  float* c01 = ws + WS_C01;
  float* c02 = ws + WS_C02;
  float* c12 = ws + WS_C12;
  float* dinv = ws + WS_DINV;

  float* adj    = out + OF_ADJ;
  float* normed = out + OF_ADJ;            // scratch inside adj region, consumed before adjwrite
  float* fe     = out + OF_FE;
  float* h0     = out + OF_NB;             // scratch inside neighbor_emb region
  float* h1     = out + OF_NB + 2304000;
  float* h2     = out + OF_NB;             // reuses h0 slot (h0 dead by then)
  float* tmp    = out + OF_FT;             // scratch inside ft/fv/fp region

  fillx_kernel<<<9000, 256, 0, stream>>>(t, v, p, fe);
  norm_kernel<<<9000, 64, 0, stream>>>(t, v, p, normed);
  spital_kernel<<<90, 256, 0, stream>>>(normed, blocks);
  dsim_kernel<<<3000, 64, 0, stream>>>(normed, c01, c02, c12);
  sparsify_kernel<<<90, 128, 0, stream>>>(blocks);
  deg_kernel<<<36, 256, 0, stream>>>(blocks, c01, c02, c12, dinv);
  normblocks_kernel<<<3516, 256, 0, stream>>>(blocks, dinv);
  adjwrite_kernel<<<9000, 256, 0, stream>>>(blocks, c01, c02, c12, dinv, adj);

  // GCNII
  gemm_kernel<<<141 * 4, 256, 0, stream>>>(fe, 512, W0, b0, h0, 9000, 0, 0.f, 0.f);
  spmm_kernel<<<9000, 256, 0, stream>>>(blocks, c01, c02, c12, dinv, h0, h0, tmp);
  gemm_kernel<<<141 * 4, 256, 0, stream>>>(tmp, 256, Ws, nullptr, h1, 9000, 1,
                                           0.4054651081081644f, 0.5945348918918356f);
  spmm_kernel<<<9000, 256, 0, stream>>>(blocks, c01, c02, c12, dinv, h1, h0, tmp);
  gemm_kernel<<<141 * 4, 256, 0, stream>>>(tmp, 256, Ws + 65536, nullptr, h2, 9000, 1,
                                           0.22314355131420976f, 0.7768564486857902f);

  outh_kernel<<<9000, 256, 0, stream>>>(h2, fe);
  outcopy_kernel<<<18000, 256, 0, stream>>>(fe, out);
}

// Round 4
// 438.006 us; speedup vs baseline: 2.1545x; 1.2779x over previous
//
#include <hip/hip_runtime.h>
#include <math.h>

#define NN 3000
#define DD 30
#define LLEN 100
#define NDIM 256
#define PI_F 3.14159265358979323846f

// ---- output layout (float offsets) ----
#define OF_FE  0          // features_e: 9000 x 512
#define OF_ADJ 4608000    // adj_la: 9000 x 9000
#define OF_NB  85608000   // neighbor_emb: 3000 x 1536
#define OF_FT  90216000   // ft|fv|fp: 3 x (3000 x 512)

// ---- workspace layout (float offsets) ----
#define WS_BLOCKS 0       // 90 * 100 * 100
#define WS_C01 900000
#define WS_C02 903000
#define WS_C12 906000
#define WS_DEG 909000     // 9000

// fused: fe[:, :256] = raw features; normed rows; cross-modality diag sims.
// 3 waves per block, one per modality; cross-dots via LDS stage.
__global__ __launch_bounds__(192) void fillnorm_kernel(const float* __restrict__ t, const float* __restrict__ v,
                                                       const float* __restrict__ p, float* __restrict__ fe,
                                                       float* __restrict__ normed, float* __restrict__ c01,
                                                       float* __restrict__ c02, float* __restrict__ c12) {
  int rem = blockIdx.x;
  int w = threadIdx.x >> 6, lane = threadIdx.x & 63;
  const float* src = (w == 0 ? t : (w == 1 ? v : p)) + (size_t)rem * NDIM;
  float4 x = ((const float4*)src)[lane];
  int r = w * NN + rem;
  ((float4*)(fe + (size_t)r * 512))[lane] = x;
  float ss = x.x*x.x + x.y*x.y + x.z*x.z + x.w*x.w;
  #pragma unroll
  for (int off = 32; off > 0; off >>= 1) ss += __shfl_xor(ss, off);
  float inv = 1.0f / sqrtf(ss);
  float4 n = make_float4(x.x*inv, x.y*inv, x.z*inv, x.w*inv);
  ((float4*)(normed + (size_t)r * NDIM))[lane] = n;
  __shared__ float NB[3][256];
  ((float4*)NB[w])[lane] = n;
  __syncthreads();
  if (w == 0) {
    float4 a = ((const float4*)NB[0])[lane];
    float4 b = ((const float4*)NB[1])[lane];
    float4 c = ((const float4*)NB[2])[lane];
    float s01 = a.x*b.x + a.y*b.y + a.z*b.z + a.w*b.w;
    float s02 = a.x*c.x + a.y*c.y + a.z*c.z + a.w*c.w;
    float s12 = b.x*c.x + b.y*c.y + b.z*c.z + b.w*c.w;
    #pragma unroll
    for (int off = 32; off > 0; off >>= 1) {
      s01 += __shfl_xor(s01, off);
      s02 += __shfl_xor(s02, off);
      s12 += __shfl_xor(s12, off);
    }
    if (lane == 0) {
      c01[rem] = 1.0f - acosf(s01 * 0.99999f) / PI_F;
      c02[rem] = 1.0f - acosf(s02 * 0.99999f) / PI_F;
      c12[rem] = 1.0f - acosf(s12 * 0.99999f) / PI_F;
    }
  }
}

// per (m,d): spital[i][j] = (1 - acos(dot_ij*0.99999)/pi) / (log(|i-j|+1)+1e-4)
#define LPAD 112
__global__ __launch_bounds__(256) void spital_kernel(const float* __restrict__ normed, float* __restrict__ blocks) {
  int b = blockIdx.x;          // m*30+d ; node base = b*100
  int base = b * 100;
  __shared__ float Ts[64][LPAD];
  int tid = threadIdx.x;
  int tn = tid & 15, tm = tid >> 4;
  float acc[7][7];
  #pragma unroll
  for (int q = 0; q < 7; ++q)
    #pragma unroll
    for (int s = 0; s < 7; ++s) acc[q][s] = 0.0f;

  for (int kk = 0; kk < 256; kk += 64) {
    for (int pp = tid; pp < 100 * 16; pp += 256) {
      int kq = pp & 15, i = pp >> 4;
      float4 vv = *(const float4*)&normed[(size_t)(base + i) * NDIM + kk + kq * 4];
      Ts[kq*4+0][i] = vv.x; Ts[kq*4+1][i] = vv.y; Ts[kq*4+2][i] = vv.z; Ts[kq*4+3][i] = vv.w;
    }
    __syncthreads();
    #pragma unroll 4
    for (int k = 0; k < 64; ++k) {
      float a[7], bb[7];
      #pragma unroll
      for (int q = 0; q < 7; ++q) { int i = tm*7+q; if (i > 99) i = 99; a[q] = Ts[k][i]; }
      #pragma unroll
      for (int s = 0; s < 7; ++s) { int j = tn*7+s; if (j > 99) j = 99; bb[s] = Ts[k][j]; }
      #pragma unroll
      for (int q = 0; q < 7; ++q)
        #pragma unroll
        for (int s = 0; s < 7; ++s) acc[q][s] += a[q] * bb[s];
    }
    __syncthreads();
  }
  #pragma unroll
  for (int q = 0; q < 7; ++q) {
    int i = tm*7+q; if (i >= 100) continue;
    #pragma unroll
    for (int s = 0; s < 7; ++s) {
      int j = tn*7+s; if (j >= 100) continue;
      float S = acc[q][s] * 0.99999f;
      float sim = 1.0f - acosf(S) / PI_F;
      int dd = i - j; if (dd < 0) dd = -dd;
      float decay = logf((float)dd + 1.0f) + 1e-4f;
      blocks[(size_t)b * 10000 + i * 100 + j] = sim / decay;
    }
  }
}

// Sequential top-K scan exploiting exact symmetry.
// spital is exactly symmetric (identical fp ops for (i,j),(j,i)); the scan
// preserves symmetry each step (col-phase e only alters column e; row e's
// rank vector == col e's). Hence one count per step, zero both (e,i),(i,e).
// Stable-rank for vi>0: cnt = #(vj < vi); zeros only tie with zeros and
// re-zeroing is a no-op. Tail: row sums + cross terms -> degree.
__global__ __launch_bounds__(128, 1) void sparsify_kernel(float* __restrict__ blocks,
                                                          const float* __restrict__ c01,
                                                          const float* __restrict__ c02,
                                                          const float* __restrict__ c12,
                                                          float* __restrict__ deg) {
  int b = blockIdx.x, m = b / DD, d = b % DD;
  __shared__ float A[10000];
  int tid = threadIdx.x;
  for (int p0 = tid; p0 < 10000; p0 += 128) A[p0] = blocks[(size_t)b * 10000 + p0];
  __syncthreads();

  for (int e = 0; e < 100; ++e) {
    float vi = 0.0f; int cnt = 0;
    if (tid < 100) {
      vi = A[e * 100 + tid];
      int c0 = 0, c1 = 0, c2 = 0, c3 = 0;
      #pragma unroll
      for (int q = 0; q < 25; ++q) {
        float4 r4 = *(const float4*)&A[e * 100 + q * 4];
        c0 += (int)(r4.x < vi); c1 += (int)(r4.y < vi);
        c2 += (int)(r4.z < vi); c3 += (int)(r4.w < vi);
      }
      cnt = (c0 + c1) + (c2 + c3);
    }
    __syncthreads();
    if (tid < 100 && cnt < 80 && vi != 0.0f) { A[e * 100 + tid] = 0.0f; A[tid * 100 + e] = 0.0f; }
    __syncthreads();
  }

  for (int p0 = tid; p0 < 10000; p0 += 128) blocks[(size_t)b * 10000 + p0] = A[p0];
  if (tid < 100) {
    float s = 0.0f;
    #pragma unroll
    for (int q = 0; q < 25; ++q) {
      float4 a4 = *(const float4*)&A[tid * 100 + q * 4];
      s += (a4.x + a4.y) + (a4.z + a4.w);
    }
    int rem = d * 100 + tid;
    float ct = (m == 0) ? c01[rem] + c02[rem] : (m == 1) ? c01[rem] + c12[rem] : c02[rem] + c12[rem];
    s += ct;
    if (s == 0.0f) s = 1e-12f;
    deg[m * NN + rem] = s;
  }
}

// one block per adjacency row: zeros + dinv-scaled diag-block segment + 2 cross
__global__ __launch_bounds__(256) void normadj_kernel(const float* __restrict__ blocks,
                                                      const float* __restrict__ c01, const float* __restrict__ c02,
                                                      const float* __restrict__ c12, const float* __restrict__ deg,
                                                      float* __restrict__ adj) {
  int r = blockIdx.x;
  int m = r / NN, rem = r % NN;
  int d = rem / 100, i = rem % 100;
  int bb = m * DD + d;
  int rbase = bb * 100;
  float* row = adj + (size_t)r * 9000;
  float4 z = make_float4(0.f, 0.f, 0.f, 0.f);
  for (int c4 = threadIdx.x; c4 < 2250; c4 += 256) ((float4*)row)[c4] = z;
  __syncthreads();
  int tid = threadIdx.x;
  float dr = 1.0f / sqrtf(deg[r]);
  if (tid < 100) {
    float dc = 1.0f / sqrtf(deg[rbase + tid]);
    row[rbase + tid] = blocks[(size_t)bb * 10000 + i * 100 + tid] * dr * dc;
  }
  if (tid == 0) {
    const float *a1, *a2; int n1, n2;
    if (m == 0)      { a1 = c01; a2 = c02; n1 = 1; n2 = 2; }
    else if (m == 1) { a1 = c01; a2 = c12; n1 = 0; n2 = 2; }
    else             { a1 = c02; a2 = c12; n1 = 0; n2 = 1; }
    row[n1 * NN + rem] = a1[rem] * dr * (1.0f / sqrtf(deg[n1 * NN + rem]));
    row[n2 * NN + rem] = a2[rem] * dr * (1.0f / sqrtf(deg[n2 * NN + rem]));
  }
}

// C = relu(A@W + bias)              (mode 0)
// C = relu(theta*(A@W) + omtheta*A) (mode 1, N==K==256)
__global__ __launch_bounds__(256) void gemm_kernel(const float* __restrict__ A, int lda,
                                                   const float* __restrict__ W, const float* __restrict__ bias,
                                                   float* __restrict__ C, int ldc, int M, int mode,
                                                   float theta, float omtheta) {
  __shared__ float As[16][64];
  __shared__ float Bs[16][64];
  int bx = blockIdx.x & 3;
  int by = blockIdx.x >> 2;
  int tid = threadIdx.x;
  int tn = tid & 15, tm = tid >> 4;
  int row0 = by * 64, col0 = bx * 64;
  float acc[4][4];
  #pragma unroll
  for (int i = 0; i < 4; ++i)
    #pragma unroll
    for (int j = 0; j < 4; ++j) acc[i][j] = 0.0f;
  int lr = tid >> 2, lc = tid & 3;
  int br = tid >> 4, bc = tid & 15;

  for (int kk = 0; kk < 256; kk += 16) {
    int ar = row0 + lr;
    float4 av = make_float4(0.f, 0.f, 0.f, 0.f);
    if (ar < M) av = *(const float4*)&A[(size_t)ar * lda + kk + lc * 4];
    As[lc*4+0][lr] = av.x; As[lc*4+1][lr] = av.y; As[lc*4+2][lr] = av.z; As[lc*4+3][lr] = av.w;
    *(float4*)&Bs[br][bc * 4] = *(const float4*)&W[(size_t)(kk + br) * 256 + col0 + bc * 4];
    __syncthreads();
    #pragma unroll
    for (int k = 0; k < 16; ++k) {
      float4 a4 = *(const float4*)&As[k][tm * 4];
      float4 b4 = *(const float4*)&Bs[k][tn * 4];
      float a[4] = {a4.x, a4.y, a4.z, a4.w};
      float bb[4] = {b4.x, b4.y, b4.z, b4.w};
      #pragma unroll
      for (int ii = 0; ii < 4; ++ii)
        #pragma unroll
        for (int jj = 0; jj < 4; ++jj) acc[ii][jj] += a[ii] * bb[jj];
    }
    __syncthreads();
  }
  #pragma unroll
  for (int ii = 0; ii < 4; ++ii) {
    int r = row0 + tm * 4 + ii;
    if (r >= M) continue;
    #pragma unroll
    for (int jj = 0; jj < 4; ++jj) {
      int c = col0 + tn * 4 + jj;
      float val = acc[ii][jj];
      if (mode == 0) val += bias[c];
      else val = theta * val + omtheta * A[(size_t)r * lda + c];
      C[(size_t)r * ldc + c] = fmaxf(val, 0.0f);
    }
  }
}

// support = 0.9 * (adj_norm @ h) + 0.1 * h0   (block-sparse adj, on-the-fly dinv)
__global__ __launch_bounds__(256) void spmm_kernel(const float* __restrict__ blocks, const float* __restrict__ c01,
                                                   const float* __restrict__ c02, const float* __restrict__ c12,
                                                   const float* __restrict__ deg, const float* __restrict__ h,
                                                   const float* __restrict__ h0, float* __restrict__ out) {
  int r = blockIdx.x;
  int f = threadIdx.x;
  int m = r / NN, rem = r % NN;
  int d = rem / 100, i = rem % 100;
  int b = m * DD + d;
  int gbase = b * 100;
  __shared__ float avs[100];
  if (f < 100) avs[f] = blocks[(size_t)b * 10000 + i * 100 + f] * (1.0f / sqrtf(deg[gbase + f]));
  __syncthreads();
  float acc = 0.0f;
  for (int j = 0; j < 100; ++j) {
    float a = avs[j];
    if (a != 0.0f) acc += a * h[((size_t)gbase + j) * 256 + f];
  }
  float dr = 1.0f / sqrtf(deg[r]);
  acc *= dr;
  const float *a1, *a2; int n1, n2;
  if (m == 0)      { a1 = c01; a2 = c02; n1 = 1; n2 = 2; }
  else if (m == 1) { a1 = c01; a2 = c12; n1 = 0; n2 = 2; }
  else             { a1 = c02; a2 = c12; n1 = 0; n2 = 1; }
  acc += a1[rem] * dr * (1.0f / sqrtf(deg[n1 * NN + rem])) * h[((size_t)n1 * NN + rem) * 256 + f];
  acc += a2[rem] * dr * (1.0f / sqrtf(deg[n2 * NN + rem])) * h[((size_t)n2 * NN + rem) * 256 + f];
  out[(size_t)r * 256 + f] = 0.9f * acc + 0.1f * h0[(size_t)r * 256 + f];
}

// neighbor_emb + ft/fv/fp from features_e (gemm2 already wrote fe[:,256:])
__global__ __launch_bounds__(256) void outfuse_kernel(const float* __restrict__ fe, float* __restrict__ out) {
  int rem = blockIdx.x, f = threadIdx.x;
  #pragma unroll
  for (int m = 0; m < 3; ++m) {
    size_t r = (size_t)(m * NN + rem);
    float xv = fe[r * 512 + f];
    float hv = fe[r * 512 + 256 + f];
    out[OF_NB + (size_t)rem * 1536 + m * 512 + f] = xv;
    out[OF_NB + (size_t)rem * 1536 + m * 512 + 256 + f] = hv;
    out[OF_FT + r * 512 + f] = xv;
    out[OF_FT + r * 512 + 256 + f] = hv;
  }
}

extern "C" void kernel_launch(void* const* d_in, const int* in_sizes, int n_in,
                              void* d_out, int out_size, void* d_ws, size_t ws_size,
                              hipStream_t stream) {
  const float* t  = (const float*)d_in[0];
  const float* v  = (const float*)d_in[1];
  const float* p  = (const float*)d_in[2];
  const float* W0 = (const float*)d_in[3];
  const float* b0 = (const float*)d_in[4];
  const float* Ws = (const float*)d_in[5];
  float* out = (float*)d_out;
  float* ws  = (float*)d_ws;

  float* blocks = ws + WS_BLOCKS;
  float* c01 = ws + WS_C01;
  float* c02 = ws + WS_C02;
  float* c12 = ws + WS_C12;
  float* deg = ws + WS_DEG;

  float* adj    = out + OF_ADJ;
  float* normed = out + OF_ADJ;            // scratch inside adj region; consumed by spital before normadj
  float* fe     = out + OF_FE;
  float* h0     = out + OF_NB;             // scratch inside neighbor_emb region
  float* h1     = out + OF_NB + 2304000;
  float* tmp    = out + OF_FT;             // scratch inside ft/fv/fp region

  fillnorm_kernel<<<3000, 192, 0, stream>>>(t, v, p, fe, normed, c01, c02, c12);
  spital_kernel<<<90, 256, 0, stream>>>(normed, blocks);
  sparsify_kernel<<<90, 128, 0, stream>>>(blocks, c01, c02, c12, deg);
  normadj_kernel<<<9000, 256, 0, stream>>>(blocks, c01, c02, c12, deg, adj);

  // GCNII
  gemm_kernel<<<141 * 4, 256, 0, stream>>>(fe, 512, W0, b0, h0, 256, 9000, 0, 0.f, 0.f);
  spmm_kernel<<<9000, 256, 0, stream>>>(blocks, c01, c02, c12, deg, h0, h0, tmp);
  gemm_kernel<<<141 * 4, 256, 0, stream>>>(tmp, 256, Ws, nullptr, h1, 256, 9000, 1,
                                           0.4054651081081644f, 0.5945348918918356f);
  spmm_kernel<<<9000, 256, 0, stream>>>(blocks, c01, c02, c12, deg, h1, h0, tmp);
  gemm_kernel<<<141 * 4, 256, 0, stream>>>(tmp, 256, Ws + 65536, nullptr, fe + 256, 512, 9000, 1,
                                           0.22314355131420976f, 0.7768564486857902f);

  outfuse_kernel<<<3000, 256, 0, stream>>>(fe, out);
}

// Round 5
// 387.678 us; speedup vs baseline: 2.4342x; 1.1298x over previous
//
#include <hip/hip_runtime.h>
#include <math.h>

#define NN 3000
#define DD 30
#define LLEN 100
#define NDIM 256
#define PI_F 3.14159265358979323846f

// ---- output layout (float offsets) ----
#define OF_FE  0          // features_e: 9000 x 512
#define OF_ADJ 4608000    // adj_la: 9000 x 9000
#define OF_NB  85608000   // neighbor_emb: 3000 x 1536
#define OF_FT  90216000   // ft|fv|fp: 3 x (3000 x 512)

// ---- workspace layout (float offsets) ----
#define WS_BLOCKS 0       // 90 * 100 * 100
#define WS_C01 900000
#define WS_C02 903000
#define WS_C12 906000
#define WS_DEG 909000     // 9000

typedef __attribute__((ext_vector_type(8))) short bf16x8;
typedef __attribute__((ext_vector_type(4))) float f32x4;

__device__ __forceinline__ unsigned short f2bf(float x) {
  unsigned int u = __float_as_uint(x);
  return (unsigned short)((u + 0x7FFFu + ((u >> 16) & 1u)) >> 16);
}

// fused: fe[:, :256] = raw features; normed rows; cross-modality diag sims.
__global__ __launch_bounds__(192) void fillnorm_kernel(const float* __restrict__ t, const float* __restrict__ v,
                                                       const float* __restrict__ p, float* __restrict__ fe,
                                                       float* __restrict__ normed, float* __restrict__ c01,
                                                       float* __restrict__ c02, float* __restrict__ c12) {
  int rem = blockIdx.x;
  int w = threadIdx.x >> 6, lane = threadIdx.x & 63;
  const float* src = (w == 0 ? t : (w == 1 ? v : p)) + (size_t)rem * NDIM;
  float4 x = ((const float4*)src)[lane];
  int r = w * NN + rem;
  ((float4*)(fe + (size_t)r * 512))[lane] = x;
  float ss = x.x*x.x + x.y*x.y + x.z*x.z + x.w*x.w;
  #pragma unroll
  for (int off = 32; off > 0; off >>= 1) ss += __shfl_xor(ss, off);
  float inv = 1.0f / sqrtf(ss);
  float4 n = make_float4(x.x*inv, x.y*inv, x.z*inv, x.w*inv);
  ((float4*)(normed + (size_t)r * NDIM))[lane] = n;
  __shared__ float NB[3][256];
  ((float4*)NB[w])[lane] = n;
  __syncthreads();
  if (w == 0) {
    float4 a = ((const float4*)NB[0])[lane];
    float4 b = ((const float4*)NB[1])[lane];
    float4 c = ((const float4*)NB[2])[lane];
    float s01 = a.x*b.x + a.y*b.y + a.z*b.z + a.w*b.w;
    float s02 = a.x*c.x + a.y*c.y + a.z*c.z + a.w*c.w;
    float s12 = b.x*c.x + b.y*c.y + b.z*c.z + b.w*c.w;
    #pragma unroll
    for (int off = 32; off > 0; off >>= 1) {
      s01 += __shfl_xor(s01, off);
      s02 += __shfl_xor(s02, off);
      s12 += __shfl_xor(s12, off);
    }
    if (lane == 0) {
      c01[rem] = 1.0f - acosf(s01 * 0.99999f) / PI_F;
      c02[rem] = 1.0f - acosf(s02 * 0.99999f) / PI_F;
      c12[rem] = 1.0f - acosf(s12 * 0.99999f) / PI_F;
    }
  }
}

// per (m,d): spital[i][j] = (1 - acos(dot_ij*0.99999)/pi) / (log(|i-j|+1)+1e-4)
#define LPAD 112
__global__ __launch_bounds__(256) void spital_kernel(const float* __restrict__ normed, float* __restrict__ blocks) {
  int b = blockIdx.x;
  int base = b * 100;
  __shared__ float Ts[64][LPAD];
  int tid = threadIdx.x;
  int tn = tid & 15, tm = tid >> 4;
  float acc[7][7];
  #pragma unroll
  for (int q = 0; q < 7; ++q)
    #pragma unroll
    for (int s = 0; s < 7; ++s) acc[q][s] = 0.0f;

  for (int kk = 0; kk < 256; kk += 64) {
    for (int pp = tid; pp < 100 * 16; pp += 256) {
      int kq = pp & 15, i = pp >> 4;
      float4 vv = *(const float4*)&normed[(size_t)(base + i) * NDIM + kk + kq * 4];
      Ts[kq*4+0][i] = vv.x; Ts[kq*4+1][i] = vv.y; Ts[kq*4+2][i] = vv.z; Ts[kq*4+3][i] = vv.w;
    }
    __syncthreads();
    #pragma unroll 4
    for (int k = 0; k < 64; ++k) {
      float a[7], bb[7];
      #pragma unroll
      for (int q = 0; q < 7; ++q) { int i = tm*7+q; if (i > 99) i = 99; a[q] = Ts[k][i]; }
      #pragma unroll
      for (int s = 0; s < 7; ++s) { int j = tn*7+s; if (j > 99) j = 99; bb[s] = Ts[k][j]; }
      #pragma unroll
      for (int q = 0; q < 7; ++q)
        #pragma unroll
        for (int s = 0; s < 7; ++s) acc[q][s] += a[q] * bb[s];
    }
    __syncthreads();
  }
  #pragma unroll
  for (int q = 0; q < 7; ++q) {
    int i = tm*7+q; if (i >= 100) continue;
    #pragma unroll
    for (int s = 0; s < 7; ++s) {
      int j = tn*7+s; if (j >= 100) continue;
      float S = acc[q][s] * 0.99999f;
      float sim = 1.0f - acosf(S) / PI_F;
      int dd = i - j; if (dd < 0) dd = -dd;
      float decay = logf((float)dd + 1.0f) + 1e-4f;
      blocks[(size_t)b * 10000 + i * 100 + j] = sim / decay;
    }
  }
}

// Sequential top-K scan, 2-step software pipeline.
// Step e zeroes only row/col e, so step e+1's input row differs from the
// pre-step-e state at exactly one element A[e+1][e]. Half-waves compute
// counts for e and e+1 concurrently; half B applies an exact correction
// after step e commits: if A[e+1][e] was zeroed (w->0), then for i!=e
// cnt += (vi>0) - (w<vi), and lane i==e treats its value as 0 (skip).
// Decisions identical to the sequential scan. Symmetry (proven rounds 2-3)
// lets one count serve both row e and col e.
__global__ __launch_bounds__(256, 1) void sparsify_kernel(float* __restrict__ blocks,
                                                          const float* __restrict__ c01,
                                                          const float* __restrict__ c02,
                                                          const float* __restrict__ c12,
                                                          float* __restrict__ deg) {
  int b = blockIdx.x, m = b / DD, d = b % DD;
  __shared__ float A[10000];
  int tid = threadIdx.x;
  for (int p0 = tid; p0 < 10000; p0 += 256) A[p0] = blocks[(size_t)b * 10000 + p0];
  __syncthreads();

  int half = tid >> 7;      // 0: step e, 1: step e+1 (speculative)
  int i = tid & 127;
  for (int e = 0; e < 100; e += 2) {
    int er = e + half;
    float vi = 0.0f; int cnt = 0;
    if (i < 100) {
      vi = A[er * 100 + i];
      int c0 = 0, c1 = 0, c2 = 0, c3 = 0;
      #pragma unroll
      for (int q = 0; q < 25; ++q) {
        float4 r4 = *(const float4*)&A[er * 100 + q * 4];
        c0 += (int)(r4.x < vi); c1 += (int)(r4.y < vi);
        c2 += (int)(r4.z < vi); c3 += (int)(r4.w < vi);
      }
      cnt = (c0 + c1) + (c2 + c3);
    }
    float w = A[(e + 1) * 100 + e];   // pre-step-e value (broadcast)
    __syncthreads();
    if (half == 0 && i < 100 && cnt < 80 && vi != 0.0f) {
      A[e * 100 + i] = 0.0f; A[i * 100 + e] = 0.0f;
    }
    __syncthreads();
    if (half == 1 && i < 100) {
      float post = A[(e + 1) * 100 + e];
      if (post == 0.0f && w != 0.0f) {      // step e zeroed our element j=e
        if (i == e) vi = 0.0f;
        else cnt += 1 - (int)(w < vi);
      }
      if (cnt < 80 && vi != 0.0f) {
        A[(e + 1) * 100 + i] = 0.0f; A[i * 100 + (e + 1)] = 0.0f;
      }
    }
    __syncthreads();
  }

  for (int p0 = tid; p0 < 10000; p0 += 256) blocks[(size_t)b * 10000 + p0] = A[p0];
  if (tid < 100) {
    float s = 0.0f;
    #pragma unroll
    for (int q = 0; q < 25; ++q) {
      float4 a4 = *(const float4*)&A[tid * 100 + q * 4];
      s += (a4.x + a4.y) + (a4.z + a4.w);
    }
    int rem = d * 100 + tid;
    float ct = (m == 0) ? c01[rem] + c02[rem] : (m == 1) ? c01[rem] + c12[rem] : c02[rem] + c12[rem];
    s += ct;
    if (s == 0.0f) s = 1e-12f;
    deg[m * NN + tid + d * 100] = s;
  }
}

// one block per adjacency row: zeros + dinv-scaled diag-block segment + 2 cross
__global__ __launch_bounds__(256) void normadj_kernel(const float* __restrict__ blocks,
                                                      const float* __restrict__ c01, const float* __restrict__ c02,
                                                      const float* __restrict__ c12, const float* __restrict__ deg,
                                                      float* __restrict__ adj) {
  int r = blockIdx.x;
  int m = r / NN, rem = r % NN;
  int d = rem / 100, i = rem % 100;
  int bb = m * DD + d;
  int rbase = bb * 100;
  float* row = adj + (size_t)r * 9000;
  float4 z = make_float4(0.f, 0.f, 0.f, 0.f);
  for (int c4 = threadIdx.x; c4 < 2250; c4 += 256) ((float4*)row)[c4] = z;
  __syncthreads();
  int tid = threadIdx.x;
  float dr = 1.0f / sqrtf(deg[r]);
  if (tid < 100) {
    float dc = 1.0f / sqrtf(deg[rbase + tid]);
    row[rbase + tid] = blocks[(size_t)bb * 10000 + i * 100 + tid] * dr * dc;
  }
  if (tid == 0) {
    const float *a1, *a2; int n1, n2;
    if (m == 0)      { a1 = c01; a2 = c02; n1 = 1; n2 = 2; }
    else if (m == 1) { a1 = c01; a2 = c12; n1 = 0; n2 = 2; }
    else             { a1 = c02; a2 = c12; n1 = 0; n2 = 1; }
    row[n1 * NN + rem] = a1[rem] * dr * (1.0f / sqrtf(deg[n1 * NN + rem]));
    row[n2 * NN + rem] = a2[rem] * dr * (1.0f / sqrtf(deg[n2 * NN + rem]));
  }
}

// bf16 MFMA GEMM, K=256 fully staged in LDS.
// C = relu(A@W + bias)              (mode 0)
// C = relu(theta*(A@W) + omtheta*A) (mode 1)
// Fragment layout (v_mfma_f32_16x16x32_bf16): A: row=lane&15, k=(lane>>4)*8+j
// (8 contiguous bf16 -> one b128); B: col=lane&15, same k; C/D: col=lane&15,
// row=(lane>>4)*4+reg  [m89-verified].
#define KP 264
__global__ __launch_bounds__(256) void gemm_kernel(const float* __restrict__ A, int lda,
                                                   const float* __restrict__ W, const float* __restrict__ bias,
                                                   float* __restrict__ C, int ldc, int M, int mode,
                                                   float theta, float omtheta) {
  __shared__ unsigned short As[64 * KP];
  __shared__ unsigned short Bs[64 * KP];
  int tid = threadIdx.x;
  int bx = blockIdx.x & 3;        // N tile (256/64)
  int by = blockIdx.x >> 2;       // M tile
  int row0 = by * 64, col0 = bx * 64;

  // stage A (64 rows x 256 k), fp32 -> bf16
  for (int idx = tid; idx < 64 * 64; idx += 256) {
    int r = idx >> 6, c4 = idx & 63;
    int gr = row0 + r;
    float4 av = make_float4(0.f, 0.f, 0.f, 0.f);
    if (gr < M) av = *(const float4*)&A[(size_t)gr * lda + c4 * 4];
    ushort4 h;
    h.x = f2bf(av.x); h.y = f2bf(av.y); h.z = f2bf(av.z); h.w = f2bf(av.w);
    *(ushort4*)&As[r * KP + c4 * 4] = h;
  }
  // stage B transposed: Bs[col][k] (64 cols x 256 k)
  for (int idx = tid; idx < 4096; idx += 256) {
    int k = idx >> 4, c4 = idx & 15;
    float4 wv = *(const float4*)&W[(size_t)k * 256 + col0 + c4 * 4];
    Bs[(c4 * 4 + 0) * KP + k] = f2bf(wv.x);
    Bs[(c4 * 4 + 1) * KP + k] = f2bf(wv.y);
    Bs[(c4 * 4 + 2) * KP + k] = f2bf(wv.z);
    Bs[(c4 * 4 + 3) * KP + k] = f2bf(wv.w);
  }
  __syncthreads();

  int wid = tid >> 6, lane = tid & 63;
  int wm = (wid >> 1) * 32, wn = (wid & 1) * 32;
  int fr = lane & 15, fk = (lane >> 4) * 8;
  f32x4 acc00 = {0.f, 0.f, 0.f, 0.f}, acc01 = acc00, acc10 = acc00, acc11 = acc00;

  #pragma unroll
  for (int ks = 0; ks < 8; ++ks) {
    int k = ks * 32 + fk;
    bf16x8 a0 = *(const bf16x8*)&As[(wm + fr) * KP + k];
    bf16x8 a1 = *(const bf16x8*)&As[(wm + 16 + fr) * KP + k];
    bf16x8 b0 = *(const bf16x8*)&Bs[(wn + fr) * KP + k];
    bf16x8 b1 = *(const bf16x8*)&Bs[(wn + 16 + fr) * KP + k];
    acc00 = __builtin_amdgcn_mfma_f32_16x16x32_bf16(a0, b0, acc00, 0, 0, 0);
    acc01 = __builtin_amdgcn_mfma_f32_16x16x32_bf16(a0, b1, acc01, 0, 0, 0);
    acc10 = __builtin_amdgcn_mfma_f32_16x16x32_bf16(a1, b0, acc10, 0, 0, 0);
    acc11 = __builtin_amdgcn_mfma_f32_16x16x32_bf16(a1, b1, acc11, 0, 0, 0);
  }

  int crow = (lane >> 4) * 2;     // *4 rows, packed as 2 row-pairs below
  int ccol = lane & 15;
  #pragma unroll
  for (int mi = 0; mi < 2; ++mi) {
    #pragma unroll
    for (int ni = 0; ni < 2; ++ni) {
      f32x4 acc = (mi == 0) ? (ni == 0 ? acc00 : acc01) : (ni == 0 ? acc10 : acc11);
      #pragma unroll
      for (int rg = 0; rg < 4; ++rg) {
        int grow = row0 + wm + mi * 16 + (lane >> 4) * 4 + rg;
        int gcol = col0 + wn + ni * 16 + ccol;
        if (grow < M) {
          float val = acc[rg];
          if (mode == 0) val += bias[gcol];
          else val = theta * val + omtheta * A[(size_t)grow * lda + gcol];
          C[(size_t)grow * ldc + gcol] = fmaxf(val, 0.0f);
        }
      }
    }
  }
  (void)crow;
}

// support = 0.9 * (adj_norm @ h) + 0.1 * h0   (block-sparse adj, on-the-fly dinv)
__global__ __launch_bounds__(256) void spmm_kernel(const float* __restrict__ blocks, const float* __restrict__ c01,
                                                   const float* __restrict__ c02, const float* __restrict__ c12,
                                                   const float* __restrict__ deg, const float* __restrict__ h,
                                                   const float* __restrict__ h0, float* __restrict__ out) {
  int r = blockIdx.x;
  int f = threadIdx.x;
  int m = r / NN, rem = r % NN;
  int d = rem / 100, i = rem % 100;
  int b = m * DD + d;
  int gbase = b * 100;
  __shared__ float avs[100];
  if (f < 100) avs[f] = blocks[(size_t)b * 10000 + i * 100 + f] * (1.0f / sqrtf(deg[gbase + f]));
  __syncthreads();
  float acc = 0.0f;
  for (int j = 0; j < 100; ++j) {
    float a = avs[j];
    if (a != 0.0f) acc += a * h[((size_t)gbase + j) * 256 + f];
  }
  float dr = 1.0f / sqrtf(deg[r]);
  acc *= dr;
  const float *a1, *a2; int n1, n2;
  if (m == 0)      { a1 = c01; a2 = c02; n1 = 1; n2 = 2; }
  else if (m == 1) { a1 = c01; a2 = c12; n1 = 0; n2 = 2; }
  else             { a1 = c02; a2 = c12; n1 = 0; n2 = 1; }
  acc += a1[rem] * dr * (1.0f / sqrtf(deg[n1 * NN + rem])) * h[((size_t)n1 * NN + rem) * 256 + f];
  acc += a2[rem] * dr * (1.0f / sqrtf(deg[n2 * NN + rem])) * h[((size_t)n2 * NN + rem) * 256 + f];
  out[(size_t)r * 256 + f] = 0.9f * acc + 0.1f * h0[(size_t)r * 256 + f];
}

// neighbor_emb + ft/fv/fp from features_e (gemm3 already wrote fe[:,256:])
__global__ __launch_bounds__(256) void outfuse_kernel(const float* __restrict__ fe, float* __restrict__ out) {
  int rem = blockIdx.x, f = threadIdx.x;
  #pragma unroll
  for (int m = 0; m < 3; ++m) {
    size_t r = (size_t)(m * NN + rem);
    float xv = fe[r * 512 + f];
    float hv = fe[r * 512 + 256 + f];
    out[OF_NB + (size_t)rem * 1536 + m * 512 + f] = xv;
    out[OF_NB + (size_t)rem * 1536 + m * 512 + 256 + f] = hv;
    out[OF_FT + r * 512 + f] = xv;
    out[OF_FT + r * 512 + 256 + f] = hv;
  }
}

extern "C" void kernel_launch(void* const* d_in, const int* in_sizes, int n_in,
                              void* d_out, int out_size, void* d_ws, size_t ws_size,
                              hipStream_t stream) {
  const float* t  = (const float*)d_in[0];
  const float* v  = (const float*)d_in[1];
  const float* p  = (const float*)d_in[2];
  const float* W0 = (const float*)d_in[3];
  const float* b0 = (const float*)d_in[4];
  const float* Ws = (const float*)d_in[5];
  float* out = (float*)d_out;
  float* ws  = (float*)d_ws;

  float* blocks = ws + WS_BLOCKS;
  float* c01 = ws + WS_C01;
  float* c02 = ws + WS_C02;
  float* c12 = ws + WS_C12;
  float* deg = ws + WS_DEG;

  float* adj    = out + OF_ADJ;
  float* normed = out + OF_ADJ;            // scratch inside adj region; consumed by spital before normadj
  float* fe     = out + OF_FE;
  float* h0     = out + OF_NB;             // scratch inside neighbor_emb region
  float* h1     = out + OF_NB + 2304000;
  float* tmp    = out + OF_FT;             // scratch inside ft/fv/fp region

  fillnorm_kernel<<<3000, 192, 0, stream>>>(t, v, p, fe, normed, c01, c02, c12);
  spital_kernel<<<90, 256, 0, stream>>>(normed, blocks);
  sparsify_kernel<<<90, 256, 0, stream>>>(blocks, c01, c02, c12, deg);
  normadj_kernel<<<9000, 256, 0, stream>>>(blocks, c01, c02, c12, deg, adj);

  // GCNII (bf16 MFMA GEMMs)
  gemm_kernel<<<141 * 4, 256, 0, stream>>>(fe, 512, W0, b0, h0, 256, 9000, 0, 0.f, 0.f);
  spmm_kernel<<<9000, 256, 0, stream>>>(blocks, c01, c02, c12, deg, h0, h0, tmp);
  gemm_kernel<<<141 * 4, 256, 0, stream>>>(tmp, 256, Ws, nullptr, h1, 256, 9000, 1,
                                           0.4054651081081644f, 0.5945348918918356f);
  spmm_kernel<<<9000, 256, 0, stream>>>(blocks, c01, c02, c12, deg, h1, h0, tmp);
  gemm_kernel<<<141 * 4, 256, 0, stream>>>(tmp, 256, Ws + 65536, nullptr, fe + 256, 512, 9000, 1,
                                           0.22314355131420976f, 0.7768564486857902f);

  outfuse_kernel<<<3000, 256, 0, stream>>>(fe, out);
}

// Round 6
// 351.069 us; speedup vs baseline: 2.6880x; 1.1043x over previous
//
#include <hip/hip_runtime.h>
#include <math.h>

#define NN 3000
#define DD 30
#define LLEN 100
#define NDIM 256
#define PI_F 3.14159265358979323846f

// ---- output layout (float offsets) ----
#define OF_FE  0          // features_e: 9000 x 512
#define OF_ADJ 4608000    // adj_la: 9000 x 9000
#define OF_NB  85608000   // neighbor_emb: 3000 x 1536
#define OF_FT  90216000   // ft|fv|fp: 3 x (3000 x 512)

// ---- workspace layout (float offsets) ----
#define WS_BLOCKS 0       // 90 * 100 * 100
#define WS_C01 900000
#define WS_C02 903000
#define WS_C12 906000
#define WS_DEG 909000     // 9000

// ---- bf16 scratch inside output regions (float offsets from region base) ----
// NB region (4.608M floats): h0bf @ +0, h1bf @ +1.2M     (each 1.152M float-slots)
// FT region (4.608M floats): t1bf @ +0, t2bf @ +1.2M, xbf @ +2.4M, WT @ +3.6M
// all consumed before outfuse overwrites NB/FT at the end.

typedef __attribute__((ext_vector_type(8))) short bf16x8;
typedef __attribute__((ext_vector_type(4))) float f32x4;

__device__ __forceinline__ unsigned short f2bf(float x) {
  unsigned int u = __float_as_uint(x);
  return (unsigned short)((u + 0x7FFFu + ((u >> 16) & 1u)) >> 16);
}
__device__ __forceinline__ float bf2f(unsigned short u) {
  return __uint_as_float((unsigned int)u << 16);
}

// transpose+convert the 3 fp32 [256][256] weight matrices -> bf16 WT[n][k]
__global__ __launch_bounds__(256) void wtrans_kernel(const float* __restrict__ W0, const float* __restrict__ Ws,
                                                     unsigned short* __restrict__ WT) {
  int blk = blockIdx.x;               // m*64 + tile
  int m = blk >> 6, t = blk & 63;
  int tr = (t >> 3) * 32, tc = (t & 7) * 32;
  const float* W = (m == 0) ? W0 : Ws + (size_t)(m - 1) * 65536;
  __shared__ float T[32][33];
  int r = threadIdx.x >> 5, c = threadIdx.x & 31;
  #pragma unroll
  for (int rr = 0; rr < 4; ++rr)
    T[r + rr * 8][c] = W[(size_t)(tr + r + rr * 8) * 256 + tc + c];
  __syncthreads();
  #pragma unroll
  for (int rr = 0; rr < 4; ++rr)
    WT[(size_t)m * 65536 + (size_t)(tc + r + rr * 8) * 256 + tr + c] = f2bf(T[c][r + rr * 8]);
}

// fused: fe[:, :256] = raw features; xbf = bf16(raw); normed rows; cross sims.
__global__ __launch_bounds__(192) void fillnorm_kernel(const float* __restrict__ t, const float* __restrict__ v,
                                                       const float* __restrict__ p, float* __restrict__ fe,
                                                       unsigned short* __restrict__ xbf,
                                                       float* __restrict__ normed, float* __restrict__ c01,
                                                       float* __restrict__ c02, float* __restrict__ c12) {
  int rem = blockIdx.x;
  int w = threadIdx.x >> 6, lane = threadIdx.x & 63;
  const float* src = (w == 0 ? t : (w == 1 ? v : p)) + (size_t)rem * NDIM;
  float4 x = ((const float4*)src)[lane];
  int r = w * NN + rem;
  ((float4*)(fe + (size_t)r * 512))[lane] = x;
  ushort4 xh;
  xh.x = f2bf(x.x); xh.y = f2bf(x.y); xh.z = f2bf(x.z); xh.w = f2bf(x.w);
  *(ushort4*)&xbf[(size_t)r * 256 + lane * 4] = xh;
  float ss = x.x*x.x + x.y*x.y + x.z*x.z + x.w*x.w;
  #pragma unroll
  for (int off = 32; off > 0; off >>= 1) ss += __shfl_xor(ss, off);
  float inv = 1.0f / sqrtf(ss);
  float4 n = make_float4(x.x*inv, x.y*inv, x.z*inv, x.w*inv);
  ((float4*)(normed + (size_t)r * NDIM))[lane] = n;
  __shared__ float NB[3][256];
  ((float4*)NB[w])[lane] = n;
  __syncthreads();
  if (w == 0) {
    float4 a = ((const float4*)NB[0])[lane];
    float4 b = ((const float4*)NB[1])[lane];
    float4 c = ((const float4*)NB[2])[lane];
    float s01 = a.x*b.x + a.y*b.y + a.z*b.z + a.w*b.w;
    float s02 = a.x*c.x + a.y*c.y + a.z*c.z + a.w*c.w;
    float s12 = b.x*c.x + b.y*c.y + b.z*c.z + b.w*c.w;
    #pragma unroll
    for (int off = 32; off > 0; off >>= 1) {
      s01 += __shfl_xor(s01, off);
      s02 += __shfl_xor(s02, off);
      s12 += __shfl_xor(s12, off);
    }
    if (lane == 0) {
      c01[rem] = 1.0f - acosf(s01 * 0.99999f) / PI_F;
      c02[rem] = 1.0f - acosf(s02 * 0.99999f) / PI_F;
      c12[rem] = 1.0f - acosf(s12 * 0.99999f) / PI_F;
    }
  }
}

// per (m,d): spital[i][j] = (1 - acos(dot_ij*0.99999)/pi) / (log(|i-j|+1)+1e-4)
#define LPAD 112
__global__ __launch_bounds__(256) void spital_kernel(const float* __restrict__ normed, float* __restrict__ blocks) {
  int b = blockIdx.x;
  int base = b * 100;
  __shared__ float Ts[64][LPAD];
  int tid = threadIdx.x;
  int tn = tid & 15, tm = tid >> 4;
  float acc[7][7];
  #pragma unroll
  for (int q = 0; q < 7; ++q)
    #pragma unroll
    for (int s = 0; s < 7; ++s) acc[q][s] = 0.0f;

  for (int kk = 0; kk < 256; kk += 64) {
    for (int pp = tid; pp < 100 * 16; pp += 256) {
      int kq = pp & 15, i = pp >> 4;
      float4 vv = *(const float4*)&normed[(size_t)(base + i) * NDIM + kk + kq * 4];
      Ts[kq*4+0][i] = vv.x; Ts[kq*4+1][i] = vv.y; Ts[kq*4+2][i] = vv.z; Ts[kq*4+3][i] = vv.w;
    }
    __syncthreads();
    #pragma unroll 4
    for (int k = 0; k < 64; ++k) {
      float a[7], bb[7];
      #pragma unroll
      for (int q = 0; q < 7; ++q) { int i = tm*7+q; if (i > 99) i = 99; a[q] = Ts[k][i]; }
      #pragma unroll
      for (int s = 0; s < 7; ++s) { int j = tn*7+s; if (j > 99) j = 99; bb[s] = Ts[k][j]; }
      #pragma unroll
      for (int q = 0; q < 7; ++q)
        #pragma unroll
        for (int s = 0; s < 7; ++s) acc[q][s] += a[q] * bb[s];
    }
    __syncthreads();
  }
  #pragma unroll
  for (int q = 0; q < 7; ++q) {
    int i = tm*7+q; if (i >= 100) continue;
    #pragma unroll
    for (int s = 0; s < 7; ++s) {
      int j = tn*7+s; if (j >= 100) continue;
      float S = acc[q][s] * 0.99999f;
      float sim = 1.0f - acosf(S) / PI_F;
      int dd = i - j; if (dd < 0) dd = -dd;
      float decay = logf((float)dd + 1.0f) + 1e-4f;
      blocks[(size_t)b * 10000 + i * 100 + j] = sim / decay;
    }
  }
}

// Sequential top-K scan, 4-deep software pipeline (512 thr = 4 x 128-lane halves).
// Step e+h's input row differs from superstep-start state only at elements
// {e..e+h-1} (each touched by exactly one in-window step). Counts for 4 steps
// run concurrently; half h applies <=3 exact corrections before its commit:
// if A[er][e+c] was zeroed (post==0, pre w!=0): lane i==e+c -> vi=0, else
// cnt += 1 - (w < vi). Decisions bit-identical to the sequential scan.
// Symmetry (established rounds 2-5): one count serves row+col.
__global__ __launch_bounds__(512, 1) void sparsify_kernel(float* __restrict__ blocks,
                                                          const float* __restrict__ c01,
                                                          const float* __restrict__ c02,
                                                          const float* __restrict__ c12,
                                                          float* __restrict__ deg) {
  int b = blockIdx.x, m = b / DD, d = b % DD;
  __shared__ float A[10000];
  int tid = threadIdx.x;
  for (int p0 = tid; p0 < 10000; p0 += 512) A[p0] = blocks[(size_t)b * 10000 + p0];
  __syncthreads();

  int h = tid >> 7;          // pipeline slot: step e+h
  int i = tid & 127;
  for (int e = 0; e < 100; e += 4) {
    int er = e + h;
    float vi = 0.0f, w0 = 0.0f, w1 = 0.0f, w2 = 0.0f;
    int cnt = 0;
    if (i < 100) {
      vi = A[er * 100 + i];
      if (h > 0) w0 = A[er * 100 + e];
      if (h > 1) w1 = A[er * 100 + e + 1];
      if (h > 2) w2 = A[er * 100 + e + 2];
      int c0 = 0, c1 = 0, c2 = 0, c3 = 0;
      #pragma unroll
      for (int q = 0; q < 25; ++q) {
        float4 r4 = *(const float4*)&A[er * 100 + q * 4];
        c0 += (int)(r4.x < vi); c1 += (int)(r4.y < vi);
        c2 += (int)(r4.z < vi); c3 += (int)(r4.w < vi);
      }
      cnt = (c0 + c1) + (c2 + c3);
    }
    __syncthreads();
    if (h == 0 && i < 100 && cnt < 80 && vi != 0.0f) {
      A[e * 100 + i] = 0.0f; A[i * 100 + e] = 0.0f;
    }
    __syncthreads();
    if (h == 1 && i < 100) {
      float p0v = A[er * 100 + e];
      if (p0v == 0.0f && w0 != 0.0f) { if (i == e) vi = 0.0f; else cnt += 1 - (int)(w0 < vi); }
      if (cnt < 80 && vi != 0.0f) { A[er * 100 + i] = 0.0f; A[i * 100 + er] = 0.0f; }
    }
    __syncthreads();
    if (h == 2 && i < 100) {
      float p0v = A[er * 100 + e], p1v = A[er * 100 + e + 1];
      if (p0v == 0.0f && w0 != 0.0f) { if (i == e)     vi = 0.0f; else cnt += 1 - (int)(w0 < vi); }
      if (p1v == 0.0f && w1 != 0.0f) { if (i == e + 1) vi = 0.0f; else cnt += 1 - (int)(w1 < vi); }
      if (cnt < 80 && vi != 0.0f) { A[er * 100 + i] = 0.0f; A[i * 100 + er] = 0.0f; }
    }
    __syncthreads();
    if (h == 3 && i < 100) {
      float p0v = A[er * 100 + e], p1v = A[er * 100 + e + 1], p2v = A[er * 100 + e + 2];
      if (p0v == 0.0f && w0 != 0.0f) { if (i == e)     vi = 0.0f; else cnt += 1 - (int)(w0 < vi); }
      if (p1v == 0.0f && w1 != 0.0f) { if (i == e + 1) vi = 0.0f; else cnt += 1 - (int)(w1 < vi); }
      if (p2v == 0.0f && w2 != 0.0f) { if (i == e + 2) vi = 0.0f; else cnt += 1 - (int)(w2 < vi); }
      if (cnt < 80 && vi != 0.0f) { A[er * 100 + i] = 0.0f; A[i * 100 + er] = 0.0f; }
    }
    __syncthreads();
  }

  for (int p0 = tid; p0 < 10000; p0 += 512) blocks[(size_t)b * 10000 + p0] = A[p0];
  if (tid < 100) {
    float s = 0.0f;
    #pragma unroll
    for (int q = 0; q < 25; ++q) {
      float4 a4 = *(const float4*)&A[tid * 100 + q * 4];
      s += (a4.x + a4.y) + (a4.z + a4.w);
    }
    int rem = d * 100 + tid;
    float ct = (m == 0) ? c01[rem] + c02[rem] : (m == 1) ? c01[rem] + c12[rem] : c02[rem] + c12[rem];
    s += ct;
    if (s == 0.0f) s = 1e-12f;
    deg[m * NN + rem] = s;
  }
}

// one block per adjacency row: zeros + dinv-scaled diag-block segment + 2 cross
__global__ __launch_bounds__(256) void normadj_kernel(const float* __restrict__ blocks,
                                                      const float* __restrict__ c01, const float* __restrict__ c02,
                                                      const float* __restrict__ c12, const float* __restrict__ deg,
                                                      float* __restrict__ adj) {
  int r = blockIdx.x;
  int m = r / NN, rem = r % NN;
  int d = rem / 100, i = rem % 100;
  int bb = m * DD + d;
  int rbase = bb * 100;
  float* row = adj + (size_t)r * 9000;
  float4 z = make_float4(0.f, 0.f, 0.f, 0.f);
  for (int c4 = threadIdx.x; c4 < 2250; c4 += 256) ((float4*)row)[c4] = z;
  __syncthreads();
  int tid = threadIdx.x;
  float dr = 1.0f / sqrtf(deg[r]);
  if (tid < 100) {
    float dc = 1.0f / sqrtf(deg[rbase + tid]);
    row[rbase + tid] = blocks[(size_t)bb * 10000 + i * 100 + tid] * dr * dc;
  }
  if (tid == 0) {
    const float *a1, *a2; int n1, n2;
    if (m == 0)      { a1 = c01; a2 = c02; n1 = 1; n2 = 2; }
    else if (m == 1) { a1 = c01; a2 = c12; n1 = 0; n2 = 2; }
    else             { a1 = c02; a2 = c12; n1 = 0; n2 = 1; }
    row[n1 * NN + rem] = a1[rem] * dr * (1.0f / sqrtf(deg[n1 * NN + rem]));
    row[n2 * NN + rem] = a2[rem] * dr * (1.0f / sqrtf(deg[n2 * NN + rem]));
  }
}

// LDS-free bf16 MFMA GEMM: A bf16 [M][256] k-contiguous, WT bf16 [n][256]
// k-contiguous -> MFMA fragments are direct global b128 loads (L2-resident).
// mode 0: relu(A@W + bias); mode 1: relu(theta*(A@W) + omtheta*A).
// Output: bf16 (Cb) when outbf, else fp32 (Cf). C/D layout per m89.
__global__ __launch_bounds__(256, 2) void gemm_kernel(const unsigned short* __restrict__ A,
                                                      const unsigned short* __restrict__ WT,
                                                      const float* __restrict__ bias,
                                                      float* __restrict__ Cf, unsigned short* __restrict__ Cb,
                                                      int ldc, int M, int mode, int outbf,
                                                      float theta, float omtheta) {
  int tid = threadIdx.x;
  int bx = blockIdx.x & 3;        // N tile (256/64)
  int by = blockIdx.x >> 2;       // M tile
  int row0 = by * 64, col0 = bx * 64;
  int wid = tid >> 6, lane = tid & 63;
  int wm = (wid >> 1) * 32, wn = (wid & 1) * 32;
  int fr = lane & 15, fk = (lane >> 4) * 8;

  int ra0 = row0 + wm + fr;       if (ra0 >= M) ra0 = M - 1;
  int ra1 = row0 + wm + 16 + fr;  if (ra1 >= M) ra1 = M - 1;
  const unsigned short* pa0 = A + (size_t)ra0 * 256 + fk;
  const unsigned short* pa1 = A + (size_t)ra1 * 256 + fk;
  const unsigned short* pb0 = WT + (size_t)(col0 + wn + fr) * 256 + fk;
  const unsigned short* pb1 = WT + (size_t)(col0 + wn + 16 + fr) * 256 + fk;

  f32x4 acc00 = {0.f, 0.f, 0.f, 0.f}, acc01 = acc00, acc10 = acc00, acc11 = acc00;
  #pragma unroll
  for (int ks = 0; ks < 8; ++ks) {
    bf16x8 a0 = *(const bf16x8*)(pa0 + ks * 32);
    bf16x8 a1 = *(const bf16x8*)(pa1 + ks * 32);
    bf16x8 b0 = *(const bf16x8*)(pb0 + ks * 32);
    bf16x8 b1 = *(const bf16x8*)(pb1 + ks * 32);
    acc00 = __builtin_amdgcn_mfma_f32_16x16x32_bf16(a0, b0, acc00, 0, 0, 0);
    acc01 = __builtin_amdgcn_mfma_f32_16x16x32_bf16(a0, b1, acc01, 0, 0, 0);
    acc10 = __builtin_amdgcn_mfma_f32_16x16x32_bf16(a1, b0, acc10, 0, 0, 0);
    acc11 = __builtin_amdgcn_mfma_f32_16x16x32_bf16(a1, b1, acc11, 0, 0, 0);
  }

  #pragma unroll
  for (int mi = 0; mi < 2; ++mi) {
    #pragma unroll
    for (int ni = 0; ni < 2; ++ni) {
      f32x4 acc = (mi == 0) ? (ni == 0 ? acc00 : acc01) : (ni == 0 ? acc10 : acc11);
      #pragma unroll
      for (int rg = 0; rg < 4; ++rg) {
        int grow = row0 + wm + mi * 16 + (lane >> 4) * 4 + rg;
        int gcol = col0 + wn + ni * 16 + (lane & 15);
        if (grow < M) {
          float val = acc[rg];
          if (mode == 0) val += bias[gcol];
          else val = theta * val + omtheta * bf2f(A[(size_t)grow * 256 + gcol]);
          val = fmaxf(val, 0.0f);
          if (outbf) Cb[(size_t)grow * ldc + gcol] = f2bf(val);
          else       Cf[(size_t)grow * ldc + gcol] = val;
        }
      }
    }
  }
}

// support = 0.9 * (adj_norm @ h) + 0.1 * h0  (block-sparse, bf16 h/h0, bf16 out)
__global__ __launch_bounds__(256) void spmm_kernel(const float* __restrict__ blocks, const float* __restrict__ c01,
                                                   const float* __restrict__ c02, const float* __restrict__ c12,
                                                   const float* __restrict__ deg,
                                                   const unsigned short* __restrict__ h,
                                                   const unsigned short* __restrict__ h0,
                                                   unsigned short* __restrict__ outb) {
  int r = blockIdx.x;
  int f = threadIdx.x;
  int m = r / NN, rem = r % NN;
  int d = rem / 100, i = rem % 100;
  int b = m * DD + d;
  int gbase = b * 100;
  __shared__ float avs[100];
  if (f < 100) avs[f] = blocks[(size_t)b * 10000 + i * 100 + f] * (1.0f / sqrtf(deg[gbase + f]));
  __syncthreads();
  float acc = 0.0f;
  for (int j = 0; j < 100; ++j) {
    float a = avs[j];
    if (a != 0.0f) acc += a * bf2f(h[((size_t)gbase + j) * 256 + f]);
  }
  float dr = 1.0f / sqrtf(deg[r]);
  acc *= dr;
  const float *a1, *a2; int n1, n2;
  if (m == 0)      { a1 = c01; a2 = c02; n1 = 1; n2 = 2; }
  else if (m == 1) { a1 = c01; a2 = c12; n1 = 0; n2 = 2; }
  else             { a1 = c02; a2 = c12; n1 = 0; n2 = 1; }
  acc += a1[rem] * dr * (1.0f / sqrtf(deg[n1 * NN + rem])) * bf2f(h[((size_t)n1 * NN + rem) * 256 + f]);
  acc += a2[rem] * dr * (1.0f / sqrtf(deg[n2 * NN + rem])) * bf2f(h[((size_t)n2 * NN + rem) * 256 + f]);
  float val = 0.9f * acc + 0.1f * bf2f(h0[(size_t)r * 256 + f]);
  outb[(size_t)r * 256 + f] = f2bf(val);
}

// neighbor_emb + ft/fv/fp from features_e (gemm3 already wrote fe[:,256:])
__global__ __launch_bounds__(256) void outfuse_kernel(const float* __restrict__ fe, float* __restrict__ out) {
  int rem = blockIdx.x, f = threadIdx.x;
  #pragma unroll
  for (int m = 0; m < 3; ++m) {
    size_t r = (size_t)(m * NN + rem);
    float xv = fe[r * 512 + f];
    float hv = fe[r * 512 + 256 + f];
    out[OF_NB + (size_t)rem * 1536 + m * 512 + f] = xv;
    out[OF_NB + (size_t)rem * 1536 + m * 512 + 256 + f] = hv;
    out[OF_FT + r * 512 + f] = xv;
    out[OF_FT + r * 512 + 256 + f] = hv;
  }
}

extern "C" void kernel_launch(void* const* d_in, const int* in_sizes, int n_in,
                              void* d_out, int out_size, void* d_ws, size_t ws_size,
                              hipStream_t stream) {
  const float* t  = (const float*)d_in[0];
  const float* v  = (const float*)d_in[1];
  const float* p  = (const float*)d_in[2];
  const float* W0 = (const float*)d_in[3];
  const float* b0 = (const float*)d_in[4];
  const float* Ws = (const float*)d_in[5];
  float* out = (float*)d_out;
  float* ws  = (float*)d_ws;

  float* blocks = ws + WS_BLOCKS;
  float* c01 = ws + WS_C01;
  float* c02 = ws + WS_C02;
  float* c12 = ws + WS_C12;
  float* deg = ws + WS_DEG;

  float* adj    = out + OF_ADJ;
  float* normed = out + OF_ADJ;            // scratch in adj region; consumed by spital before normadj
  float* fe     = out + OF_FE;

  unsigned short* h0b = (unsigned short*)(out + OF_NB);             // 9000x256 bf16
  unsigned short* h1b = (unsigned short*)(out + OF_NB + 1200000);
  unsigned short* t1b = (unsigned short*)(out + OF_FT);
  unsigned short* t2b = (unsigned short*)(out + OF_FT + 1200000);
  unsigned short* xbf = (unsigned short*)(out + OF_FT + 2400000);
  unsigned short* WT  = (unsigned short*)(out + OF_FT + 3600000);   // 3 x 256x256 bf16

  wtrans_kernel<<<192, 256, 0, stream>>>(W0, Ws, WT);
  fillnorm_kernel<<<3000, 192, 0, stream>>>(t, v, p, fe, xbf, normed, c01, c02, c12);
  spital_kernel<<<90, 256, 0, stream>>>(normed, blocks);
  sparsify_kernel<<<90, 512, 0, stream>>>(blocks, c01, c02, c12, deg);
  normadj_kernel<<<9000, 256, 0, stream>>>(blocks, c01, c02, c12, deg, adj);

  // GCNII (LDS-free bf16 MFMA GEMMs)
  gemm_kernel<<<141 * 4, 256, 0, stream>>>(xbf, WT, b0, nullptr, h0b, 256, 9000, 0, 1, 0.f, 0.f);
  spmm_kernel<<<9000, 256, 0, stream>>>(blocks, c01, c02, c12, deg, h0b, h0b, t1b);
  gemm_kernel<<<141 * 4, 256, 0, stream>>>(t1b, WT + 65536, b0, nullptr, h1b, 256, 9000, 1, 1,
                                           0.4054651081081644f, 0.5945348918918356f);
  spmm_kernel<<<9000, 256, 0, stream>>>(blocks, c01, c02, c12, deg, h1b, h0b, t2b);
  gemm_kernel<<<141 * 4, 256, 0, stream>>>(t2b, WT + 131072, b0, fe + 256, nullptr, 512, 9000, 1, 0,
                                           0.22314355131420976f, 0.7768564486857902f);

  outfuse_kernel<<<3000, 256, 0, stream>>>(fe, out);
}

// Round 7
// 315.078 us; speedup vs baseline: 2.9951x; 1.1142x over previous
//
#include <hip/hip_runtime.h>
#include <math.h>

#define NN 3000
#define DD 30
#define LLEN 100
#define NDIM 256
#define PI_F 3.14159265358979323846f

// ---- output layout (float offsets) ----
#define OF_FE  0          // features_e: 9000 x 512
#define OF_ADJ 4608000    // adj_la: 9000 x 9000
#define OF_NB  85608000   // neighbor_emb: 3000 x 1536
#define OF_FT  90216000   // ft|fv|fp: 3 x (3000 x 512)

// ---- workspace layout (float offsets) ----
#define WS_BLOCKS 0       // 90 * 100 * 100
#define WS_C01 900000
#define WS_C02 903000
#define WS_C12 906000
#define WS_DEG 909000     // 9000

// ---- bf16 scratch inside output regions (float offsets from region base) ----
// NB region: h0b @ +0, h1b @ +1.2M          (dead before outfuse writes NB)
// FT region: t1b @ +0, t2b @ +1.2M, xbf @ +2.4M, WT @ +3.6M (dead before outfuse)

typedef __attribute__((ext_vector_type(8))) short bf16x8;
typedef __attribute__((ext_vector_type(4))) float f32x4;

__device__ __forceinline__ unsigned short f2bf(float x) {
  unsigned int u = __float_as_uint(x);
  return (unsigned short)((u + 0x7FFFu + ((u >> 16) & 1u)) >> 16);
}
__device__ __forceinline__ float bf2f(unsigned short u) {
  return __uint_as_float((unsigned int)u << 16);
}

// ============ K1: fillnorm (3000 blocks) + wtrans (192 blocks) ============
__global__ __launch_bounds__(256) void prep_kernel(const float* __restrict__ t, const float* __restrict__ v,
                                                   const float* __restrict__ p, float* __restrict__ fe,
                                                   unsigned short* __restrict__ xbf, float* __restrict__ normed,
                                                   float* __restrict__ c01, float* __restrict__ c02,
                                                   float* __restrict__ c12,
                                                   const float* __restrict__ W0, const float* __restrict__ Ws,
                                                   unsigned short* __restrict__ WT) {
  __shared__ float smem[1056];
  int bid = blockIdx.x;
  if (bid < 3000) {
    int rem = bid;
    int w = threadIdx.x >> 6, lane = threadIdx.x & 63;
    if (w < 3) {
      const float* src = (w == 0 ? t : (w == 1 ? v : p)) + (size_t)rem * NDIM;
      float4 x = ((const float4*)src)[lane];
      int r = w * NN + rem;
      ((float4*)(fe + (size_t)r * 512))[lane] = x;
      ushort4 xh;
      xh.x = f2bf(x.x); xh.y = f2bf(x.y); xh.z = f2bf(x.z); xh.w = f2bf(x.w);
      *(ushort4*)&xbf[(size_t)r * 256 + lane * 4] = xh;
      float ss = x.x*x.x + x.y*x.y + x.z*x.z + x.w*x.w;
      #pragma unroll
      for (int off = 32; off > 0; off >>= 1) ss += __shfl_xor(ss, off);
      float inv = 1.0f / sqrtf(ss);
      float4 n = make_float4(x.x*inv, x.y*inv, x.z*inv, x.w*inv);
      ((float4*)(normed + (size_t)r * NDIM))[lane] = n;
      ((float4*)&smem[w * 256])[lane] = n;
    }
    __syncthreads();
    if (w == 0) {
      float4 a = ((const float4*)&smem[0])[lane];
      float4 b = ((const float4*)&smem[256])[lane];
      float4 c = ((const float4*)&smem[512])[lane];
      float s01 = a.x*b.x + a.y*b.y + a.z*b.z + a.w*b.w;
      float s02 = a.x*c.x + a.y*c.y + a.z*c.z + a.w*c.w;
      float s12 = b.x*c.x + b.y*c.y + b.z*c.z + b.w*c.w;
      #pragma unroll
      for (int off = 32; off > 0; off >>= 1) {
        s01 += __shfl_xor(s01, off);
        s02 += __shfl_xor(s02, off);
        s12 += __shfl_xor(s12, off);
      }
      if (lane == 0) {
        c01[rem] = 1.0f - acosf(s01 * 0.99999f) / PI_F;
        c02[rem] = 1.0f - acosf(s02 * 0.99999f) / PI_F;
        c12[rem] = 1.0f - acosf(s12 * 0.99999f) / PI_F;
      }
    }
  } else {
    // transpose+convert one 32x32 tile of one weight matrix -> bf16 WT[n][k]
    int blk = bid - 3000;
    int m = blk >> 6, tt = blk & 63;
    int tr = (tt >> 3) * 32, tc = (tt & 7) * 32;
    const float* W = (m == 0) ? W0 : Ws + (size_t)(m - 1) * 65536;
    int r = threadIdx.x >> 5, c = threadIdx.x & 31;
    #pragma unroll
    for (int rr = 0; rr < 4; ++rr)
      smem[(r + rr * 8) * 33 + c] = W[(size_t)(tr + r + rr * 8) * 256 + tc + c];
    __syncthreads();
    #pragma unroll
    for (int rr = 0; rr < 4; ++rr)
      WT[(size_t)m * 65536 + (size_t)(tc + r + rr * 8) * 256 + tr + c] = f2bf(smem[c * 33 + r + rr * 8]);
  }
}

// ============ LDS-free bf16 MFMA GEMM body ============
// A bf16 [M][256] k-contig, WT bf16 [n][256] k-contig -> fragments via b128.
// mode 0: relu(A@W + bias); mode 1: relu(theta*(A@W) + omtheta*A).
__device__ __forceinline__ void gemm_body(int gb, const unsigned short* __restrict__ A,
                                          const unsigned short* __restrict__ WT,
                                          const float* __restrict__ bias,
                                          float* __restrict__ Cf, unsigned short* __restrict__ Cb,
                                          int ldc, int M, int mode, int outbf,
                                          float theta, float omtheta) {
  int tid = threadIdx.x;
  int bx = gb & 3, by = gb >> 2;
  int row0 = by * 64, col0 = bx * 64;
  int wid = tid >> 6, lane = tid & 63;
  int wm = (wid >> 1) * 32, wn = (wid & 1) * 32;
  int fr = lane & 15, fk = (lane >> 4) * 8;

  int ra0 = row0 + wm + fr;       if (ra0 >= M) ra0 = M - 1;
  int ra1 = row0 + wm + 16 + fr;  if (ra1 >= M) ra1 = M - 1;
  const unsigned short* pa0 = A + (size_t)ra0 * 256 + fk;
  const unsigned short* pa1 = A + (size_t)ra1 * 256 + fk;
  const unsigned short* pb0 = WT + (size_t)(col0 + wn + fr) * 256 + fk;
  const unsigned short* pb1 = WT + (size_t)(col0 + wn + 16 + fr) * 256 + fk;

  f32x4 acc00 = {0.f, 0.f, 0.f, 0.f}, acc01 = acc00, acc10 = acc00, acc11 = acc00;
  #pragma unroll
  for (int ks = 0; ks < 8; ++ks) {
    bf16x8 a0 = *(const bf16x8*)(pa0 + ks * 32);
    bf16x8 a1 = *(const bf16x8*)(pa1 + ks * 32);
    bf16x8 b0 = *(const bf16x8*)(pb0 + ks * 32);
    bf16x8 b1 = *(const bf16x8*)(pb1 + ks * 32);
    acc00 = __builtin_amdgcn_mfma_f32_16x16x32_bf16(a0, b0, acc00, 0, 0, 0);
    acc01 = __builtin_amdgcn_mfma_f32_16x16x32_bf16(a0, b1, acc01, 0, 0, 0);
    acc10 = __builtin_amdgcn_mfma_f32_16x16x32_bf16(a1, b0, acc10, 0, 0, 0);
    acc11 = __builtin_amdgcn_mfma_f32_16x16x32_bf16(a1, b1, acc11, 0, 0, 0);
  }

  #pragma unroll
  for (int mi = 0; mi < 2; ++mi) {
    #pragma unroll
    for (int ni = 0; ni < 2; ++ni) {
      f32x4 acc = (mi == 0) ? (ni == 0 ? acc00 : acc01) : (ni == 0 ? acc10 : acc11);
      #pragma unroll
      for (int rg = 0; rg < 4; ++rg) {
        int grow = row0 + wm + mi * 16 + (lane >> 4) * 4 + rg;
        int gcol = col0 + wn + ni * 16 + (lane & 15);
        if (grow < M) {
          float val = acc[rg];
          if (mode == 0) val += bias[gcol];
          else val = theta * val + omtheta * bf2f(A[(size_t)grow * 256 + gcol]);
          val = fmaxf(val, 0.0f);
          if (outbf) Cb[(size_t)grow * ldc + gcol] = f2bf(val);
          else       Cf[(size_t)grow * ldc + gcol] = val;
        }
      }
    }
  }
}

// ============ K2: spital (90 blocks) + gemm1 (564 blocks) ============
#define LPAD 112
__global__ __launch_bounds__(256) void spital_gemm1_kernel(const float* __restrict__ normed,
                                                           float* __restrict__ blocks,
                                                           const unsigned short* __restrict__ xbf,
                                                           const unsigned short* __restrict__ WT,
                                                           const float* __restrict__ b0,
                                                           unsigned short* __restrict__ h0b) {
  __shared__ float Ts[64 * LPAD];
  int bid = blockIdx.x;
  if (bid >= 90) {
    gemm_body(bid - 90, xbf, WT, b0, nullptr, h0b, 256, 9000, 0, 1, 0.f, 0.f);
    return;
  }
  int b = bid;
  int base = b * 100;
  int tid = threadIdx.x;
  int tn = tid & 15, tm = tid >> 4;
  float acc[7][7];
  #pragma unroll
  for (int q = 0; q < 7; ++q)
    #pragma unroll
    for (int s = 0; s < 7; ++s) acc[q][s] = 0.0f;

  for (int kk = 0; kk < 256; kk += 64) {
    for (int pp = tid; pp < 100 * 16; pp += 256) {
      int kq = pp & 15, i = pp >> 4;
      float4 vv = *(const float4*)&normed[(size_t)(base + i) * NDIM + kk + kq * 4];
      Ts[(kq*4+0) * LPAD + i] = vv.x; Ts[(kq*4+1) * LPAD + i] = vv.y;
      Ts[(kq*4+2) * LPAD + i] = vv.z; Ts[(kq*4+3) * LPAD + i] = vv.w;
    }
    __syncthreads();
    #pragma unroll 4
    for (int k = 0; k < 64; ++k) {
      float a[7], bb[7];
      #pragma unroll
      for (int q = 0; q < 7; ++q) { int i = tm*7+q; if (i > 99) i = 99; a[q] = Ts[k * LPAD + i]; }
      #pragma unroll
      for (int s = 0; s < 7; ++s) { int j = tn*7+s; if (j > 99) j = 99; bb[s] = Ts[k * LPAD + j]; }
      #pragma unroll
      for (int q = 0; q < 7; ++q)
        #pragma unroll
        for (int s = 0; s < 7; ++s) acc[q][s] += a[q] * bb[s];
    }
    __syncthreads();
  }
  #pragma unroll
  for (int q = 0; q < 7; ++q) {
    int i = tm*7+q; if (i >= 100) continue;
    #pragma unroll
    for (int s = 0; s < 7; ++s) {
      int j = tn*7+s; if (j >= 100) continue;
      float S = acc[q][s] * 0.99999f;
      float sim = 1.0f - acosf(S) / PI_F;
      int dd = i - j; if (dd < 0) dd = -dd;
      float decay = logf((float)dd + 1.0f) + 1e-4f;
      blocks[(size_t)b * 10000 + i * 100 + j] = sim / decay;
    }
  }
}

// ============ K3: sparsify (90 blocks) + adj zero-fill (2048 blocks) ============
// Sequential top-K scan, 4-deep software pipeline (4 x 128-lane halves).
// Step e+h's input row differs from superstep-start state only at elements
// {e..e+h-1}; half h applies <=3 exact O(1) corrections before its commit.
// Decisions bit-identical to the sequential reference scan (symmetry proven
// rounds 2-5: one count serves row+col). Fill blocks stream-zero adj (324 MB)
// concurrently -- pure write-BW work overlapping the latency-bound scan.
__global__ __launch_bounds__(512, 1) void sparsify_fill_kernel(float* __restrict__ blocks,
                                                               const float* __restrict__ c01,
                                                               const float* __restrict__ c02,
                                                               const float* __restrict__ c12,
                                                               float* __restrict__ deg,
                                                               float* __restrict__ adj) {
  __shared__ float A[10000];
  int bid = blockIdx.x;
  int tid = threadIdx.x;
  if (bid >= 90) {
    float4 z = make_float4(0.f, 0.f, 0.f, 0.f);
    float4* adj4 = (float4*)adj;
    for (size_t u = (size_t)(bid - 90) * 512 + tid; u < 20250000u; u += 2048u * 512u)
      adj4[u] = z;
    return;
  }
  int b = bid, m = b / DD, d = b % DD;
  for (int p0 = tid; p0 < 10000; p0 += 512) A[p0] = blocks[(size_t)b * 10000 + p0];
  __syncthreads();

  int h = tid >> 7;          // pipeline slot: step e+h
  int i = tid & 127;
  for (int e = 0; e < 100; e += 4) {
    int er = e + h;
    float vi = 0.0f, w0 = 0.0f, w1 = 0.0f, w2 = 0.0f;
    int cnt = 0;
    if (i < 100) {
      vi = A[er * 100 + i];
      if (h > 0) w0 = A[er * 100 + e];
      if (h > 1) w1 = A[er * 100 + e + 1];
      if (h > 2) w2 = A[er * 100 + e + 2];
      int cA = 0, cB = 0, cC = 0, cD = 0;
      #pragma unroll
      for (int q = 0; q < 25; ++q) {
        float4 r4 = *(const float4*)&A[er * 100 + q * 4];
        cA += (int)(r4.x < vi); cB += (int)(r4.y < vi);
        cC += (int)(r4.z < vi); cD += (int)(r4.w < vi);
      }
      cnt = (cA + cB) + (cC + cD);
    }
    __syncthreads();
    if (h == 0 && i < 100 && cnt < 80 && vi != 0.0f) {
      A[e * 100 + i] = 0.0f; A[i * 100 + e] = 0.0f;
    }
    __syncthreads();
    if (h == 1 && i < 100) {
      float p0v = A[er * 100 + e];
      if (p0v == 0.0f && w0 != 0.0f) { if (i == e) vi = 0.0f; else cnt += 1 - (int)(w0 < vi); }
      if (cnt < 80 && vi != 0.0f) { A[er * 100 + i] = 0.0f; A[i * 100 + er] = 0.0f; }
    }
    __syncthreads();
    if (h == 2 && i < 100) {
      float p0v = A[er * 100 + e], p1v = A[er * 100 + e + 1];
      if (p0v == 0.0f && w0 != 0.0f) { if (i == e)     vi = 0.0f; else cnt += 1 - (int)(w0 < vi); }
      if (p1v == 0.0f && w1 != 0.0f) { if (i == e + 1) vi = 0.0f; else cnt += 1 - (int)(w1 < vi); }
      if (cnt < 80 && vi != 0.0f) { A[er * 100 + i] = 0.0f; A[i * 100 + er] = 0.0f; }
    }
    __syncthreads();
    if (h == 3 && i < 100) {
      float p0v = A[er * 100 + e], p1v = A[er * 100 + e + 1], p2v = A[er * 100 + e + 2];
      if (p0v == 0.0f && w0 != 0.0f) { if (i == e)     vi = 0.0f; else cnt += 1 - (int)(w0 < vi); }
      if (p1v == 0.0f && w1 != 0.0f) { if (i == e + 1) vi = 0.0f; else cnt += 1 - (int)(w1 < vi); }
      if (p2v == 0.0f && w2 != 0.0f) { if (i == e + 2) vi = 0.0f; else cnt += 1 - (int)(w2 < vi); }
      if (cnt < 80 && vi != 0.0f) { A[er * 100 + i] = 0.0f; A[i * 100 + er] = 0.0f; }
    }
    __syncthreads();
  }

  for (int p0 = tid; p0 < 10000; p0 += 512) blocks[(size_t)b * 10000 + p0] = A[p0];
  if (tid < 100) {
    float s = 0.0f;
    #pragma unroll
    for (int q = 0; q < 25; ++q) {
      float4 a4 = *(const float4*)&A[tid * 100 + q * 4];
      s += (a4.x + a4.y) + (a4.z + a4.w);
    }
    int rem = d * 100 + tid;
    float ct = (m == 0) ? c01[rem] + c02[rem] : (m == 1) ? c01[rem] + c12[rem] : c02[rem] + c12[rem];
    s += ct;
    if (s == 0.0f) s = 1e-12f;
    deg[m * NN + rem] = s;
  }
}

// ============ spmm (+ optional adj nonzero writes) ============
// support = 0.9 * (adj_norm @ h) + 0.1 * h0; when wadj: also writes the
// normalized row entries into dense adj (zero-filled by K3).
__global__ __launch_bounds__(256) void spmm_kernel(const float* __restrict__ blocks, const float* __restrict__ c01,
                                                   const float* __restrict__ c02, const float* __restrict__ c12,
                                                   const float* __restrict__ deg,
                                                   const unsigned short* __restrict__ h,
                                                   const unsigned short* __restrict__ h0,
                                                   unsigned short* __restrict__ outb,
                                                   float* __restrict__ adj, int wadj) {
  int r = blockIdx.x;
  int f = threadIdx.x;
  int m = r / NN, rem = r % NN;
  int d = rem / 100, i = rem % 100;
  int b = m * DD + d;
  int gbase = b * 100;
  __shared__ float avs[100];
  if (f < 100) avs[f] = blocks[(size_t)b * 10000 + i * 100 + f] * (1.0f / sqrtf(deg[gbase + f]));
  __syncthreads();
  float dr = 1.0f / sqrtf(deg[r]);
  const float *a1, *a2; int n1, n2;
  if (m == 0)      { a1 = c01; a2 = c02; n1 = 1; n2 = 2; }
  else if (m == 1) { a1 = c01; a2 = c12; n1 = 0; n2 = 2; }
  else             { a1 = c02; a2 = c12; n1 = 0; n2 = 1; }
  float x1 = a1[rem] * dr * (1.0f / sqrtf(deg[n1 * NN + rem]));
  float x2 = a2[rem] * dr * (1.0f / sqrtf(deg[n2 * NN + rem]));
  if (wadj) {
    float* row = adj + (size_t)r * 9000;
    if (f < 100) row[gbase + f] = avs[f] * dr;
    if (f == 0) { row[n1 * NN + rem] = x1; row[n2 * NN + rem] = x2; }
  }
  float acc = 0.0f;
  for (int j = 0; j < 100; ++j) {
    float a = avs[j];
    if (a != 0.0f) acc += a * bf2f(h[((size_t)gbase + j) * 256 + f]);
  }
  acc *= dr;
  acc += x1 * bf2f(h[((size_t)n1 * NN + rem) * 256 + f]);
  acc += x2 * bf2f(h[((size_t)n2 * NN + rem) * 256 + f]);
  float val = 0.9f * acc + 0.1f * bf2f(h0[(size_t)r * 256 + f]);
  outb[(size_t)r * 256 + f] = f2bf(val);
}

// ============ standalone GEMM dispatch ============
__global__ __launch_bounds__(256, 2) void gemm_kernel(const unsigned short* __restrict__ A,
                                                      const unsigned short* __restrict__ WT,
                                                      const float* __restrict__ bias,
                                                      float* __restrict__ Cf, unsigned short* __restrict__ Cb,
                                                      int ldc, int M, int mode, int outbf,
                                                      float theta, float omtheta) {
  gemm_body(blockIdx.x, A, WT, bias, Cf, Cb, ldc, M, mode, outbf, theta, omtheta);
}

// ============ K8: neighbor_emb + ft/fv/fp from features_e ============
__global__ __launch_bounds__(256) void outfuse_kernel(const float* __restrict__ fe, float* __restrict__ out) {
  int rem = blockIdx.x, f = threadIdx.x;
  #pragma unroll
  for (int m = 0; m < 3; ++m) {
    size_t r = (size_t)(m * NN + rem);
    float xv = fe[r * 512 + f];
    float hv = fe[r * 512 + 256 + f];
    out[OF_NB + (size_t)rem * 1536 + m * 512 + f] = xv;
    out[OF_NB + (size_t)rem * 1536 + m * 512 + 256 + f] = hv;
    out[OF_FT + r * 512 + f] = xv;
    out[OF_FT + r * 512 + 256 + f] = hv;
  }
}

extern "C" void kernel_launch(void* const* d_in, const int* in_sizes, int n_in,
                              void* d_out, int out_size, void* d_ws, size_t ws_size,
                              hipStream_t stream) {
  const float* t  = (const float*)d_in[0];
  const float* v  = (const float*)d_in[1];
  const float* p  = (const float*)d_in[2];
  const float* W0 = (const float*)d_in[3];
  const float* b0 = (const float*)d_in[4];
  const float* Ws = (const float*)d_in[5];
  float* out = (float*)d_out;
  float* ws  = (float*)d_ws;

  float* blocks = ws + WS_BLOCKS;
  float* c01 = ws + WS_C01;
  float* c02 = ws + WS_C02;
  float* c12 = ws + WS_C12;
  float* deg = ws + WS_DEG;

  float* adj    = out + OF_ADJ;
  float* normed = out + OF_ADJ;            // scratch in adj region; consumed by K2 before K3's fill
  float* fe     = out + OF_FE;

  unsigned short* h0b = (unsigned short*)(out + OF_NB);             // 9000x256 bf16
  unsigned short* h1b = (unsigned short*)(out + OF_NB + 1200000);
  unsigned short* t1b = (unsigned short*)(out + OF_FT);
  unsigned short* t2b = (unsigned short*)(out + OF_FT + 1200000);
  unsigned short* xbf = (unsigned short*)(out + OF_FT + 2400000);
  unsigned short* WT  = (unsigned short*)(out + OF_FT + 3600000);   // 3 x 256x256 bf16

  // K1: features copy/convert + row norms + cross sims + weight transpose
  prep_kernel<<<3000 + 192, 256, 0, stream>>>(t, v, p, fe, xbf, normed, c01, c02, c12, W0, Ws, WT);
  // K2: per-dialogue gram/spital + gemm1 (independent work, one dispatch)
  spital_gemm1_kernel<<<90 + 564, 256, 0, stream>>>(normed, blocks, xbf, WT, b0, h0b);
  // K3: sequential sparsify scan overlapped with 324 MB adj zero-fill
  sparsify_fill_kernel<<<90 + 2048, 512, 0, stream>>>(blocks, c01, c02, c12, deg, adj);
  // K4: spmm1 + scatter normalized adj nonzeros
  spmm_kernel<<<9000, 256, 0, stream>>>(blocks, c01, c02, c12, deg, h0b, h0b, t1b, adj, 1);
  // K5..K7: GCNII tail
  gemm_kernel<<<564, 256, 0, stream>>>(t1b, WT + 65536, b0, nullptr, h1b, 256, 9000, 1, 1,
                                       0.4054651081081644f, 0.5945348918918356f);
  spmm_kernel<<<9000, 256, 0, stream>>>(blocks, c01, c02, c12, deg, h1b, h0b, t2b, nullptr, 0);
  gemm_kernel<<<564, 256, 0, stream>>>(t2b, WT + 131072, b0, fe + 256, nullptr, 512, 9000, 1, 0,
                                       0.22314355131420976f, 0.7768564486857902f);
  // K8: fan out features_e -> neighbor_emb, ft/fv/fp
  outfuse_kernel<<<3000, 256, 0, stream>>>(fe, out);
}

// Round 8
// 246.723 us; speedup vs baseline: 3.8249x; 1.2770x over previous
//
#include <hip/hip_runtime.h>
#include <math.h>

#define NN 3000
#define DD 30
#define NDIM 256
#define PI_F 3.14159265358979323846f

// ---- output layout (float offsets) ----
#define OF_FE  0          // features_e: 9000 x 512
#define OF_ADJ 4608000    // adj_la: 9000 x 9000
#define OF_NB  85608000   // neighbor_emb: 3000 x 1536
#define OF_FT  90216000   // ft|fv|fp: 3 x (3000 x 512)

// ---- workspace layout (float offsets) ----
#define WS_BLOCKS 0       // 90 * 100 * 100
#define WS_C01 900000
#define WS_C02 903000
#define WS_C12 906000
#define WS_DEG 909000     // 9000

// scratch in output regions (all consumed before final writers):
// NB: h0b @ +0 (1.152M fl), h1b @ +1.2M  (KE overwrites NB at the end)
// FT: WT @ +3.6M (98.3K fl)              (KE overwrites FT at the end)

typedef __attribute__((ext_vector_type(8))) short bf16x8;
typedef __attribute__((ext_vector_type(4))) float f32x4;

__device__ __forceinline__ unsigned short f2bf(float x) {
  unsigned int u = __float_as_uint(x);
  return (unsigned short)((u + 0x7FFFu + ((u >> 16) & 1u)) >> 16);
}
__device__ __forceinline__ float bf2f(unsigned short u) {
  return __uint_as_float((unsigned int)u << 16);
}
__device__ __forceinline__ const float* xrow(int r, const float* t, const float* v, const float* p) {
  if (r < NN) return t + (size_t)r * NDIM;
  if (r < 2*NN) return v + (size_t)(r - NN) * NDIM;
  return p + (size_t)(r - 2*NN) * NDIM;
}
__device__ __forceinline__ bf16x8 ld8_f32(const float* q) {
  float4 a = *(const float4*)q;
  float4 b = *(const float4*)(q + 4);
  bf16x8 r;
  r[0] = (short)f2bf(a.x); r[1] = (short)f2bf(a.y); r[2] = (short)f2bf(a.z); r[3] = (short)f2bf(a.w);
  r[4] = (short)f2bf(b.x); r[5] = (short)f2bf(b.y); r[6] = (short)f2bf(b.z); r[7] = (short)f2bf(b.w);
  return r;
}

// ================= KA: prep(3000) | wtrans(192) | spital-selfnorm(90) =================
#define LPAD 112
__global__ __launch_bounds__(256) void ka_kernel(const float* __restrict__ t, const float* __restrict__ v,
                                                 const float* __restrict__ p, float* __restrict__ fe,
                                                 float* __restrict__ c01, float* __restrict__ c02,
                                                 float* __restrict__ c12,
                                                 const float* __restrict__ W0, const float* __restrict__ Ws,
                                                 unsigned short* __restrict__ WT,
                                                 float* __restrict__ blocks) {
  __shared__ float smem[7280];
  int bid = blockIdx.x, tid = threadIdx.x;

  if (bid < 3000) {           // prep: fe x-half + cross sims
    int rem = bid;
    int w = tid >> 6, lane = tid & 63;
    if (w < 3) {
      const float* src = (w == 0 ? t : (w == 1 ? v : p)) + (size_t)rem * NDIM;
      float4 x = ((const float4*)src)[lane];
      int r = w * NN + rem;
      ((float4*)(fe + (size_t)r * 512))[lane] = x;
      float ss = x.x*x.x + x.y*x.y + x.z*x.z + x.w*x.w;
      #pragma unroll
      for (int off = 32; off > 0; off >>= 1) ss += __shfl_xor(ss, off);
      float inv = 1.0f / sqrtf(ss);
      float4 n = make_float4(x.x*inv, x.y*inv, x.z*inv, x.w*inv);
      ((float4*)&smem[w * 256])[lane] = n;
    }
    __syncthreads();
    if (w == 0) {
      float4 a = ((const float4*)&smem[0])[lane];
      float4 b = ((const float4*)&smem[256])[lane];
      float4 c = ((const float4*)&smem[512])[lane];
      float s01 = a.x*b.x + a.y*b.y + a.z*b.z + a.w*b.w;
      float s02 = a.x*c.x + a.y*c.y + a.z*c.z + a.w*c.w;
      float s12 = b.x*c.x + b.y*c.y + b.z*c.z + b.w*c.w;
      #pragma unroll
      for (int off = 32; off > 0; off >>= 1) {
        s01 += __shfl_xor(s01, off);
        s02 += __shfl_xor(s02, off);
        s12 += __shfl_xor(s12, off);
      }
      if (lane == 0) {
        c01[rem] = 1.0f - acosf(s01 * 0.99999f) / PI_F;
        c02[rem] = 1.0f - acosf(s02 * 0.99999f) / PI_F;
        c12[rem] = 1.0f - acosf(s12 * 0.99999f) / PI_F;
      }
    }
    return;
  }

  if (bid < 3192) {           // wtrans: 32x32 tile transpose fp32 -> bf16 WT[n][k]
    int blk = bid - 3000;
    int m = blk >> 6, tt = blk & 63;
    int tr = (tt >> 3) * 32, tc = (tt & 7) * 32;
    const float* W = (m == 0) ? W0 : Ws + (size_t)(m - 1) * 65536;
    int r = tid >> 5, c = tid & 31;
    #pragma unroll
    for (int rr = 0; rr < 4; ++rr)
      smem[(r + rr * 8) * 33 + c] = W[(size_t)(tr + r + rr * 8) * 256 + tc + c];
    __syncthreads();
    #pragma unroll
    for (int rr = 0; rr < 4; ++rr)
      WT[(size_t)m * 65536 + (size_t)(tc + r + rr * 8) * 256 + tr + c] = f2bf(smem[c * 33 + r + rr * 8]);
    return;
  }

  // spital with self-normalization
  int b = bid - 3192;
  int m = b / DD, d = b % DD;
  const float* src = (m == 0 ? t : (m == 1 ? v : p)) + (size_t)(d * 100) * NDIM;
  float* Ts = smem;
  float* nrm = &smem[7168];
  if (tid < 200) {
    int i = tid >> 1, hf = tid & 1;
    const float* rp = src + (size_t)i * 256 + hf * 128;
    float ss = 0.0f;
    #pragma unroll
    for (int q = 0; q < 32; ++q) {
      float4 x = ((const float4*)rp)[q];
      ss += x.x*x.x + x.y*x.y + x.z*x.z + x.w*x.w;
    }
    ss += __shfl_xor(ss, 1);
    if (hf == 0) nrm[i] = 1.0f / sqrtf(ss);
  }
  __syncthreads();

  int tn = tid & 15, tm = tid >> 4;
  float acc[7][7];
  #pragma unroll
  for (int q = 0; q < 7; ++q)
    #pragma unroll
    for (int s = 0; s < 7; ++s) acc[q][s] = 0.0f;

  for (int kk = 0; kk < 256; kk += 64) {
    for (int pp = tid; pp < 1600; pp += 256) {
      int kq = pp & 15, i = pp >> 4;
      float4 vv = *(const float4*)&src[(size_t)i * 256 + kk + kq * 4];
      float sc = nrm[i];
      Ts[(kq*4+0) * LPAD + i] = vv.x * sc; Ts[(kq*4+1) * LPAD + i] = vv.y * sc;
      Ts[(kq*4+2) * LPAD + i] = vv.z * sc; Ts[(kq*4+3) * LPAD + i] = vv.w * sc;
    }
    __syncthreads();
    #pragma unroll 4
    for (int k = 0; k < 64; ++k) {
      float a[7], bb[7];
      #pragma unroll
      for (int q = 0; q < 7; ++q) { int i = tm*7+q; if (i > 99) i = 99; a[q] = Ts[k * LPAD + i]; }
      #pragma unroll
      for (int s = 0; s < 7; ++s) { int j = tn*7+s; if (j > 99) j = 99; bb[s] = Ts[k * LPAD + j]; }
      #pragma unroll
      for (int q = 0; q < 7; ++q)
        #pragma unroll
        for (int s = 0; s < 7; ++s) acc[q][s] += a[q] * bb[s];
    }
    __syncthreads();
  }
  #pragma unroll
  for (int q = 0; q < 7; ++q) {
    int i = tm*7+q; if (i >= 100) continue;
    #pragma unroll
    for (int s = 0; s < 7; ++s) {
      int j = tn*7+s; if (j >= 100) continue;
      float S = acc[q][s] * 0.99999f;
      float sim = 1.0f - acosf(S) / PI_F;
      int dd = i - j; if (dd < 0) dd = -dd;
      float decay = logf((float)dd + 1.0f) + 1e-4f;
      blocks[(size_t)b * 10000 + i * 100 + j] = sim / decay;
    }
  }
}

// ================= gemm1 body: fp32 A (t/v/p) x bf16 WT -> h0b bf16 =================
__device__ __forceinline__ void gemm1_body(int gb, const float* __restrict__ t, const float* __restrict__ v,
                                           const float* __restrict__ p,
                                           const unsigned short* __restrict__ WT,
                                           const float* __restrict__ b0,
                                           unsigned short* __restrict__ h0b, int tid) {
  int bx = gb & 3, by = gb >> 2;
  int row0 = by * 64, col0 = bx * 64;
  int wid = tid >> 6, lane = tid & 63;
  int wm = (wid >> 1) * 32, wn = (wid & 1) * 32;
  int fr = lane & 15, fk = (lane >> 4) * 8;
  int ra0 = row0 + wm + fr;       if (ra0 > 8999) ra0 = 8999;
  int ra1 = row0 + wm + 16 + fr;  if (ra1 > 8999) ra1 = 8999;
  const float* pa0 = xrow(ra0, t, v, p) + fk;
  const float* pa1 = xrow(ra1, t, v, p) + fk;
  const unsigned short* pb0 = WT + (size_t)(col0 + wn + fr) * 256 + fk;
  const unsigned short* pb1 = WT + (size_t)(col0 + wn + 16 + fr) * 256 + fk;

  f32x4 a00 = {0.f,0.f,0.f,0.f}, a01 = a00, a10 = a00, a11 = a00;
  #pragma unroll
  for (int ks = 0; ks < 8; ++ks) {
    bf16x8 A0 = ld8_f32(pa0 + ks * 32);
    bf16x8 A1 = ld8_f32(pa1 + ks * 32);
    bf16x8 B0 = *(const bf16x8*)(pb0 + ks * 32);
    bf16x8 B1 = *(const bf16x8*)(pb1 + ks * 32);
    a00 = __builtin_amdgcn_mfma_f32_16x16x32_bf16(A0, B0, a00, 0, 0, 0);
    a01 = __builtin_amdgcn_mfma_f32_16x16x32_bf16(A0, B1, a01, 0, 0, 0);
    a10 = __builtin_amdgcn_mfma_f32_16x16x32_bf16(A1, B0, a10, 0, 0, 0);
    a11 = __builtin_amdgcn_mfma_f32_16x16x32_bf16(A1, B1, a11, 0, 0, 0);
  }
  #pragma unroll
  for (int mi = 0; mi < 2; ++mi) {
    #pragma unroll
    for (int ni = 0; ni < 2; ++ni) {
      f32x4 acc = (mi == 0) ? (ni == 0 ? a00 : a01) : (ni == 0 ? a10 : a11);
      #pragma unroll
      for (int rg = 0; rg < 4; ++rg) {
        int grow = row0 + wm + mi * 16 + (lane >> 4) * 4 + rg;
        int gcol = col0 + wn + ni * 16 + (lane & 15);
        if (grow < 9000) {
          float val = fmaxf(acc[rg] + b0[gcol], 0.0f);
          h0b[(size_t)grow * 256 + gcol] = f2bf(val);
        }
      }
    }
  }
}

// ====== KB: sparsify(90) | adj zero-fill(2048) | gemm1(282 blocks x 2 units) ======
__global__ __launch_bounds__(512, 1) void kb_kernel(float* __restrict__ blocks,
                                                    const float* __restrict__ c01, const float* __restrict__ c02,
                                                    const float* __restrict__ c12, float* __restrict__ deg,
                                                    float* __restrict__ adj,
                                                    const float* __restrict__ t, const float* __restrict__ v,
                                                    const float* __restrict__ p,
                                                    const unsigned short* __restrict__ WT,
                                                    const float* __restrict__ b0,
                                                    unsigned short* __restrict__ h0b) {
  __shared__ float A[10000];
  int bid = blockIdx.x, tid = threadIdx.x;

  if (bid >= 2138) {                         // gemm1, two 64x64 tiles per block
    int gb = (bid - 2138) * 2 + (tid >> 8);
    gemm1_body(gb, t, v, p, WT, b0, h0b, tid & 255);
    return;
  }
  if (bid >= 90) {                           // stream-zero adj (324 MB)
    float4 z = make_float4(0.f, 0.f, 0.f, 0.f);
    float4* adj4 = (float4*)adj;
    for (size_t u = (size_t)(bid - 90) * 512 + tid; u < 20250000u; u += 2048u * 512u)
      adj4[u] = z;
    return;
  }

  // sparsify: 4-deep pipelined sequential scan (bit-identical decisions, rounds 4-7)
  int b = bid, m = b / DD, d = b % DD;
  for (int p0 = tid; p0 < 10000; p0 += 512) A[p0] = blocks[(size_t)b * 10000 + p0];
  __syncthreads();
  int h = tid >> 7, i = tid & 127;
  for (int e = 0; e < 100; e += 4) {
    int er = e + h;
    float vi = 0.0f, w0 = 0.0f, w1 = 0.0f, w2 = 0.0f;
    int cnt = 0;
    if (i < 100) {
      vi = A[er * 100 + i];
      if (h > 0) w0 = A[er * 100 + e];
      if (h > 1) w1 = A[er * 100 + e + 1];
      if (h > 2) w2 = A[er * 100 + e + 2];
      int cA = 0, cB = 0, cC = 0, cD = 0;
      #pragma unroll
      for (int q = 0; q < 25; ++q) {
        float4 r4 = *(const float4*)&A[er * 100 + q * 4];
        cA += (int)(r4.x < vi); cB += (int)(r4.y < vi);
        cC += (int)(r4.z < vi); cD += (int)(r4.w < vi);
      }
      cnt = (cA + cB) + (cC + cD);
    }
    __syncthreads();
    if (h == 0 && i < 100 && cnt < 80 && vi != 0.0f) { A[e * 100 + i] = 0.0f; A[i * 100 + e] = 0.0f; }
    __syncthreads();
    if (h == 1 && i < 100) {
      float p0v = A[er * 100 + e];
      if (p0v == 0.0f && w0 != 0.0f) { if (i == e) vi = 0.0f; else cnt += 1 - (int)(w0 < vi); }
      if (cnt < 80 && vi != 0.0f) { A[er * 100 + i] = 0.0f; A[i * 100 + er] = 0.0f; }
    }
    __syncthreads();
    if (h == 2 && i < 100) {
      float p0v = A[er * 100 + e], p1v = A[er * 100 + e + 1];
      if (p0v == 0.0f && w0 != 0.0f) { if (i == e)     vi = 0.0f; else cnt += 1 - (int)(w0 < vi); }
      if (p1v == 0.0f && w1 != 0.0f) { if (i == e + 1) vi = 0.0f; else cnt += 1 - (int)(w1 < vi); }
      if (cnt < 80 && vi != 0.0f) { A[er * 100 + i] = 0.0f; A[i * 100 + er] = 0.0f; }
    }
    __syncthreads();
    if (h == 3 && i < 100) {
      float p0v = A[er * 100 + e], p1v = A[er * 100 + e + 1], p2v = A[er * 100 + e + 2];
      if (p0v == 0.0f && w0 != 0.0f) { if (i == e)     vi = 0.0f; else cnt += 1 - (int)(w0 < vi); }
      if (p1v == 0.0f && w1 != 0.0f) { if (i == e + 1) vi = 0.0f; else cnt += 1 - (int)(w1 < vi); }
      if (p2v == 0.0f && w2 != 0.0f) { if (i == e + 2) vi = 0.0f; else cnt += 1 - (int)(w2 < vi); }
      if (cnt < 80 && vi != 0.0f) { A[er * 100 + i] = 0.0f; A[i * 100 + er] = 0.0f; }
    }
    __syncthreads();
  }
  for (int p0 = tid; p0 < 10000; p0 += 512) blocks[(size_t)b * 10000 + p0] = A[p0];
  if (tid < 100) {
    float s = 0.0f;
    #pragma unroll
    for (int q = 0; q < 25; ++q) {
      float4 a4 = *(const float4*)&A[tid * 100 + q * 4];
      s += (a4.x + a4.y) + (a4.z + a4.w);
    }
    int rem = d * 100 + tid;
    float ct = (m == 0) ? c01[rem] + c02[rem] : (m == 1) ? c01[rem] + c12[rem] : c02[rem] + c12[rem];
    s += ct;
    if (s == 0.0f) s = 1e-12f;
    deg[m * NN + rem] = s;
  }
}

// ====== KC/KD: fused spmm (MFMA) + GCNII GEMM per (m,d), 90 blocks ======
// sup = 0.9*(AV@H*dr + cross) + 0.1*hskip ; out = relu(theta*(sup@W) + omtheta*sup)
#define AVP 136
#define HTP 136
#define SUPP 264
__global__ __launch_bounds__(256, 1) void spmmgemm_kernel(const float* __restrict__ blocks,
                                                          const float* __restrict__ c01, const float* __restrict__ c02,
                                                          const float* __restrict__ c12, const float* __restrict__ deg,
                                                          const unsigned short* __restrict__ hin,
                                                          const unsigned short* __restrict__ hskip,
                                                          const unsigned short* __restrict__ WTl,
                                                          unsigned short* __restrict__ hout,
                                                          float* __restrict__ fe,
                                                          float* __restrict__ adj, int wadj,
                                                          float theta, float omtheta) {
  __shared__ unsigned short av[112 * AVP];
  __shared__ unsigned short hT[256 * HTP];
  __shared__ unsigned short sup[112 * SUPP];
  __shared__ float dcj[112], x1s[112], x2s[112];

  int b = blockIdx.x, m = b / DD, d = b % DD;
  int gbase = b * 100;              // == m*NN + d*100 (global node base)
  int rem0 = d * 100;
  int tid = threadIdx.x;
  int n1, n2; const float *a1, *a2;
  if (m == 0)      { a1 = c01; a2 = c02; n1 = 1; n2 = 2; }
  else if (m == 1) { a1 = c01; a2 = c12; n1 = 0; n2 = 2; }
  else             { a1 = c02; a2 = c12; n1 = 0; n2 = 1; }

  if (tid < 100) {
    int rem = rem0 + tid;
    float dr_ = 1.0f / sqrtf(deg[gbase + tid]);
    dcj[tid] = dr_;
    x1s[tid] = a1[rem] * dr_ * (1.0f / sqrtf(deg[n1 * NN + rem]));
    x2s[tid] = a2[rem] * dr_ * (1.0f / sqrtf(deg[n2 * NN + rem]));
  }
  __syncthreads();

  // stage AV (col-scaled, bf16) + zero its K-pad; stage hT[f][j] + zero K-pad
  for (int pp = tid; pp < 10000; pp += 256) {
    int i = pp / 100, j = pp % 100;
    av[i * AVP + j] = f2bf(blocks[(size_t)b * 10000 + pp] * dcj[j]);
  }
  for (int pp = tid; pp < 100 * 28; pp += 256) {
    int i = pp / 28, j = 100 + pp % 28;
    av[i * AVP + j] = 0;
  }
  {
    const unsigned short* hcol = hin + (size_t)gbase * 256 + tid;
    #pragma unroll 4
    for (int j = 0; j < 100; ++j) hT[tid * HTP + j] = hcol[(size_t)j * 256];
    #pragma unroll
    for (int j = 100; j < 128; ++j) hT[tid * HTP + j] = 0;
  }
  __syncthreads();

  int wid = tid >> 6, lane = tid & 63;
  int fr = lane & 15, fko = (lane >> 4) * 8;
  int wn = wid * 64;
  int rbase = (lane >> 4) * 4;

  // MFMA phase 1: D(112x256) = AV(112x128) @ H ; this wave: cols [wn, wn+64)
  f32x4 dacc[7][4];
  #pragma unroll
  for (int rt = 0; rt < 7; ++rt)
    #pragma unroll
    for (int ct = 0; ct < 4; ++ct) dacc[rt][ct] = (f32x4){0.f, 0.f, 0.f, 0.f};
  #pragma unroll
  for (int ks = 0; ks < 4; ++ks) {
    bf16x8 bfr[4];
    #pragma unroll
    for (int ct = 0; ct < 4; ++ct)
      bfr[ct] = *(const bf16x8*)&hT[(wn + ct * 16 + fr) * HTP + ks * 32 + fko];
    #pragma unroll
    for (int rt = 0; rt < 7; ++rt) {
      bf16x8 afr = *(const bf16x8*)&av[(rt * 16 + fr) * AVP + ks * 32 + fko];
      #pragma unroll
      for (int ct = 0; ct < 4; ++ct)
        dacc[rt][ct] = __builtin_amdgcn_mfma_f32_16x16x32_bf16(afr, bfr[ct], dacc[rt][ct], 0, 0, 0);
    }
  }
  // epilogue 1: support with row scale + cross-modality + skip -> sup (bf16)
  size_t hb1 = ((size_t)n1 * NN + rem0) * 256;
  size_t hb2 = ((size_t)n2 * NN + rem0) * 256;
  size_t hbs = (size_t)gbase * 256;
  #pragma unroll
  for (int rt = 0; rt < 7; ++rt) {
    #pragma unroll
    for (int ct = 0; ct < 4; ++ct) {
      int col = wn + ct * 16 + fr;
      #pragma unroll
      for (int rg = 0; rg < 4; ++rg) {
        int rr = rt * 16 + rbase + rg;
        if (rr < 100) {
          float val = dacc[rt][ct][rg] * dcj[rr]
                    + x1s[rr] * bf2f(hin[hb1 + (size_t)rr * 256 + col])
                    + x2s[rr] * bf2f(hin[hb2 + (size_t)rr * 256 + col]);
          val = 0.9f * val + 0.1f * bf2f(hskip[hbs + (size_t)rr * 256 + col]);
          sup[rr * SUPP + col] = f2bf(val);
        }
      }
    }
  }
  // adj nonzero scatter (layer 1 only)
  if (wadj) {
    for (int pp = tid; pp < 10000; pp += 256) {
      int i = pp / 100, j = pp % 100;
      adj[(size_t)(gbase + i) * 9000 + gbase + j] = bf2f(av[i * AVP + j]) * dcj[i];
    }
    if (tid < 100) {
      float* rowp = adj + (size_t)(gbase + tid) * 9000;
      int rem = rem0 + tid;
      rowp[(size_t)n1 * NN + rem] = x1s[tid];
      rowp[(size_t)n2 * NN + rem] = x2s[tid];
    }
  }
  __syncthreads();

  // MFMA phase 2: C(112x256) = sup(112x256) @ W
  f32x4 cacc[7][4];
  #pragma unroll
  for (int rt = 0; rt < 7; ++rt)
    #pragma unroll
    for (int ct = 0; ct < 4; ++ct) cacc[rt][ct] = (f32x4){0.f, 0.f, 0.f, 0.f};
  #pragma unroll
  for (int ks = 0; ks < 8; ++ks) {
    bf16x8 bfr[4];
    #pragma unroll
    for (int ct = 0; ct < 4; ++ct)
      bfr[ct] = *(const bf16x8*)&WTl[(size_t)(wn + ct * 16 + fr) * 256 + ks * 32 + fko];
    #pragma unroll
    for (int rt = 0; rt < 7; ++rt) {
      bf16x8 afr = *(const bf16x8*)&sup[(rt * 16 + fr) * SUPP + ks * 32 + fko];
      #pragma unroll
      for (int ct = 0; ct < 4; ++ct)
        cacc[rt][ct] = __builtin_amdgcn_mfma_f32_16x16x32_bf16(afr, bfr[ct], cacc[rt][ct], 0, 0, 0);
    }
  }
  // epilogue 2: h_next = relu(theta*C + omtheta*sup)
  #pragma unroll
  for (int rt = 0; rt < 7; ++rt) {
    #pragma unroll
    for (int ct = 0; ct < 4; ++ct) {
      int col = wn + ct * 16 + fr;
      #pragma unroll
      for (int rg = 0; rg < 4; ++rg) {
        int rr = rt * 16 + rbase + rg;
        if (rr < 100) {
          float sv = bf2f(sup[rr * SUPP + col]);
          float val = fmaxf(theta * cacc[rt][ct][rg] + omtheta * sv, 0.0f);
          if (hout) hout[(size_t)(gbase + rr) * 256 + col] = f2bf(val);
          else      fe[(size_t)(gbase + rr) * 512 + 256 + col] = val;
        }
      }
    }
  }
}

// ================= KE: neighbor_emb + ft/fv/fp fan-out =================
__global__ __launch_bounds__(256) void outfuse_kernel(const float* __restrict__ fe, float* __restrict__ out) {
  int rem = blockIdx.x, f = threadIdx.x;
  #pragma unroll
  for (int m = 0; m < 3; ++m) {
    size_t r = (size_t)(m * NN + rem);
    float xv = fe[r * 512 + f];
    float hv = fe[r * 512 + 256 + f];
    out[OF_NB + (size_t)rem * 1536 + m * 512 + f] = xv;
    out[OF_NB + (size_t)rem * 1536 + m * 512 + 256 + f] = hv;
    out[OF_FT + r * 512 + f] = xv;
    out[OF_FT + r * 512 + 256 + f] = hv;
  }
}

extern "C" void kernel_launch(void* const* d_in, const int* in_sizes, int n_in,
                              void* d_out, int out_size, void* d_ws, size_t ws_size,
                              hipStream_t stream) {
  const float* t  = (const float*)d_in[0];
  const float* v  = (const float*)d_in[1];
  const float* p  = (const float*)d_in[2];
  const float* W0 = (const float*)d_in[3];
  const float* b0 = (const float*)d_in[4];
  const float* Ws = (const float*)d_in[5];
  float* out = (float*)d_out;
  float* ws  = (float*)d_ws;

  float* blocks = ws + WS_BLOCKS;
  float* c01 = ws + WS_C01;
  float* c02 = ws + WS_C02;
  float* c12 = ws + WS_C12;
  float* deg = ws + WS_DEG;

  float* adj = out + OF_ADJ;
  float* fe  = out + OF_FE;

  unsigned short* h0b = (unsigned short*)(out + OF_NB);             // 9000x256 bf16
  unsigned short* h1b = (unsigned short*)(out + OF_NB + 1200000);
  unsigned short* WT  = (unsigned short*)(out + OF_FT + 3600000);   // 3 x 256x256 bf16

  // KA: prep | wtrans | spital(self-norm)
  ka_kernel<<<3282, 256, 0, stream>>>(t, v, p, fe, c01, c02, c12, W0, Ws, WT, blocks);
  // KB: sparsify | 324MB adj zero-fill | gemm1 (x @ W0 + b0 -> h0)
  kb_kernel<<<2420, 512, 0, stream>>>(blocks, c01, c02, c12, deg, adj, t, v, p, WT, b0, h0b);
  // KC: layer 1 (spmm-MFMA + adj scatter + GEMM) -> h1
  spmmgemm_kernel<<<90, 256, 0, stream>>>(blocks, c01, c02, c12, deg, h0b, h0b, WT + 65536,
                                          h1b, nullptr, adj, 1,
                                          0.4054651081081644f, 0.5945348918918356f);
  // KD: layer 2 -> fe[:,256:]
  spmmgemm_kernel<<<90, 256, 0, stream>>>(blocks, c01, c02, c12, deg, h1b, h0b, WT + 131072,
                                          nullptr, fe, adj, 0,
                                          0.22314355131420976f, 0.7768564486857902f);
  // KE: fan out
  outfuse_kernel<<<3000, 256, 0, stream>>>(fe, out);
}